// Round 4
// baseline (254.437 us; speedup 1.0000x reference)
//
#include <hip/hip_runtime.h>
#include <hip/hip_bf16.h>

#define S_LEN 4096
#define BATCH 8
#define DMODEL 1024
#define HDIM 256
#define NTYPES 8
#define KMAX 20
#define NSLOT (BATCH*KMAX)
#define THRESH 0.4f
#define LN_EPS 1e-5f
#define RSQRT2 0.70710678118654752f

// d_out offsets (f32 elements), reference return order
#define O_SCORES 0
#define O_ENH    32768
#define O_TLOG   196608
#define O_ESC    197888
#define O_TPROB  198048
#define O_TYPE   199328
#define O_VALIDK 199488

// ws layout (4-byte units)
#define WS_SCORES   0        // 32768 f32
#define WS_SPSTART  32768    // 16384 i32
#define WS_SPLEN    49152    // 16384 i32
#define WS_SPAVG    65536    // 16384 f32
#define WS_NSP      81920    // 8 i32
#define WS_SELSTART 81936    // 160 i32
#define WS_SELLEN   82096    // 160 i32
#define WS_SELAVG   82256    // 160 f32
#define WS_SELVALID 82416    // 160 f32
// W1 hi/lo f16, transposed + chunked + LDS-image-swizzled (k_prep bakes it)
#define WS_W1TC_HI  82576    // 131072 f32 units = 262144 f16
#define WS_W1TC_LO  213648   // 131072 f32 units

typedef _Float16 f16x8 __attribute__((ext_vector_type(8)));
typedef float f32x16 __attribute__((ext_vector_type(16)));

__device__ __forceinline__ float gelu_exact(float v) {
    return 0.5f * v * (1.0f + erff(v * RSQRT2));
}
// swizzle key: spreads fixed-kg fragment reads across all 8 LDS 16B-slots
__device__ __forceinline__ int kkey(int r) { return (r ^ (r >> 2)) & 3; }

// ---------------- K0: W1 -> chunked hi/lo f16 LDS-image ----------------
// image[chunk c][ n*32 + ((j^kkey(n))*8) + e ] = W1[c*32 + j*8 + e][n]
__global__ __launch_bounds__(256) void k_prep(
    const float* __restrict__ W1, _Float16* __restrict__ TH,
    _Float16* __restrict__ TL)
{
    const int c = blockIdx.x;     // k-chunk 0..31
    const int n = threadIdx.x;    // col 0..255
#pragma unroll
    for (int j = 0; j < 4; j++) {
        f16x8 hv, lv;
#pragma unroll
        for (int e = 0; e < 8; e++) {
            float w = W1[(size_t)(c * 32 + j * 8 + e) * HDIM + n];
            _Float16 h = (_Float16)w;
            hv[e] = h;
            lv[e] = (_Float16)(w - (float)h);
        }
        int off = c * 8192 + n * 32 + ((j ^ kkey(n)) * 8);
        *(f16x8*)&TH[off] = hv;
        *(f16x8*)&TL[off] = lv;
    }
}

// ---------------- K1: scorer MLP via 32x32x16 split-f16 MFMA ----------------
// 256 blocks x 512 thr; tile 128 tok x 256 col; BK=32; wave tile 64x64
__global__ __launch_bounds__(512) void k_score2(
    const float* __restrict__ X, const _Float16* __restrict__ TH,
    const _Float16* __restrict__ TL, const float* __restrict__ B1,
    const float* __restrict__ G, const float* __restrict__ BE,
    const float* __restrict__ W2, const float* __restrict__ B2,
    const int* __restrict__ MASK, float* __restrict__ scf,
    float* __restrict__ out)
{
    union SM {
        struct {
            _Float16 Ah[4096], Al[4096];   // 128 rows x 32 k (swizzled)
            _Float16 Bh[8192], Bl[8192];   // 256 cols x 32 k (swizzled)
        } s;                                // 48 KB
        struct { float part2[128 * 5]; float mul[128]; float rsl[128]; } e;
    };
    __shared__ SM sm;

    const int tid = threadIdx.x;
    const int l = tid & 63;
    const int wid = tid >> 6;
    const int wm = (wid >> 2) * 64;   // wave token offset {0,64}
    const int wn = (wid & 3) * 64;    // wave col offset {0,64,128,192}
    const int lr = l & 31;            // frag row/col lane
    const int lh = l >> 5;            // k-half
    const int tok0 = blockIdx.x * 128;

    // staging ids: thread covers 8 floats of A (row, k-group)
    const int arow = tid >> 2, akg = tid & 3;
    const float* xptr = X + (size_t)(tok0 + arow) * DMODEL + akg * 8;

    f32x16 acc[2][2];
#pragma unroll
    for (int mi = 0; mi < 2; mi++)
#pragma unroll
        for (int ni = 0; ni < 2; ni++) acc[mi][ni] = (f32x16)0.0f;

    // prefetch registers
    float4 xa, xb;
    f16x8 pbh0, pbh1, pbl0, pbl1;

    {   // prefetch chunk 0
        xa = *(const float4*)(xptr);
        xb = *(const float4*)(xptr + 4);
        pbh0 = *(const f16x8*)&TH[tid * 16];
        pbh1 = *(const f16x8*)&TH[tid * 16 + 8];
        pbl0 = *(const f16x8*)&TL[tid * 16];
        pbl1 = *(const f16x8*)&TL[tid * 16 + 8];
    }

    const int aoff = arow * 32 + ((akg ^ kkey(arow)) * 8);

    for (int c = 0; c < 32; ++c) {
        __syncthreads();   // previous compute done; LDS free
        // convert + write A staged regs
        {
            float xv[8] = {xa.x, xa.y, xa.z, xa.w, xb.x, xb.y, xb.z, xb.w};
            f16x8 ah, al;
#pragma unroll
            for (int e = 0; e < 8; e++) {
                _Float16 h = (_Float16)xv[e];
                ah[e] = h;
                al[e] = (_Float16)(xv[e] - (float)h);
            }
            *(f16x8*)&sm.s.Ah[aoff] = ah;
            *(f16x8*)&sm.s.Al[aoff] = al;
        }
        // write B staged regs (linear copy; swizzle pre-baked in image)
        *(f16x8*)&sm.s.Bh[tid * 16] = pbh0;
        *(f16x8*)&sm.s.Bh[tid * 16 + 8] = pbh1;
        *(f16x8*)&sm.s.Bl[tid * 16] = pbl0;
        *(f16x8*)&sm.s.Bl[tid * 16 + 8] = pbl1;
        __syncthreads();   // LDS ready

        // prefetch next chunk (issues overlap MFMA below)
        if (c < 31) {
            int cn = c + 1;
            xa = *(const float4*)(xptr + cn * 32);
            xb = *(const float4*)(xptr + cn * 32 + 4);
            pbh0 = *(const f16x8*)&TH[cn * 8192 + tid * 16];
            pbh1 = *(const f16x8*)&TH[cn * 8192 + tid * 16 + 8];
            pbl0 = *(const f16x8*)&TL[cn * 8192 + tid * 16];
            pbl1 = *(const f16x8*)&TL[cn * 8192 + tid * 16 + 8];
        }

        // compute: 2 k-substeps x 2 ni x 2 mi x 3 passes = 24 MFMA
#pragma unroll
        for (int s = 0; s < 2; ++s) {
            const int kg = s * 2 + lh;
            f16x8 fah[2], fal[2];
#pragma unroll
            for (int mi = 0; mi < 2; mi++) {
                int row = wm + mi * 32 + lr;
                int o = row * 32 + ((kg ^ kkey(row)) * 8);
                fah[mi] = *(const f16x8*)&sm.s.Ah[o];
                fal[mi] = *(const f16x8*)&sm.s.Al[o];
            }
#pragma unroll
            for (int ni = 0; ni < 2; ni++) {
                int col = wn + ni * 32 + lr;
                int o = col * 32 + ((kg ^ kkey(col)) * 8);
                f16x8 fbh = *(const f16x8*)&sm.s.Bh[o];
                f16x8 fbl = *(const f16x8*)&sm.s.Bl[o];
#pragma unroll
                for (int mi = 0; mi < 2; mi++) {
                    acc[mi][ni] = __builtin_amdgcn_mfma_f32_32x32x16_f16(fah[mi], fbh, acc[mi][ni], 0, 0, 0);
                    acc[mi][ni] = __builtin_amdgcn_mfma_f32_32x32x16_f16(fal[mi], fbh, acc[mi][ni], 0, 0, 0);
                    acc[mi][ni] = __builtin_amdgcn_mfma_f32_32x32x16_f16(fah[mi], fbl, acc[mi][ni], 0, 0, 0);
                }
            }
        }
    }

    __syncthreads();   // staging dead; union becomes epilogue arrays

    // C/D layout (32x32): col = wn+ni*32+lr, row = wm+mi*32+(r&3)+8*(r>>2)+4*lh
    const int wnid = wn >> 6;  // 0..3
    float bcol[2], gcol[2], becol[2], wcol[2];
#pragma unroll
    for (int ni = 0; ni < 2; ni++) {
        int colg = wn + ni * 32 + lr;
        bcol[ni] = B1[colg];
        gcol[ni] = G[colg];
        becol[ni] = BE[colg];
        wcol[ni] = W2[colg];
    }
#pragma unroll
    for (int mi = 0; mi < 2; mi++)
#pragma unroll
        for (int ni = 0; ni < 2; ni++)
#pragma unroll
            for (int r = 0; r < 16; r++) acc[mi][ni][r] += bcol[ni];

    // pass 1: row means (shfl-butterfly over the 32 lr lanes = 64 cols/wave)
#pragma unroll
    for (int mi = 0; mi < 2; mi++)
#pragma unroll
        for (int r = 0; r < 16; r++) {
            float p = acc[mi][0][r] + acc[mi][1][r];
            p += __shfl_xor(p, 1);  p += __shfl_xor(p, 2);
            p += __shfl_xor(p, 4);  p += __shfl_xor(p, 8);
            p += __shfl_xor(p, 16);
            int row = wm + mi * 32 + (r & 3) + 8 * (r >> 2) + 4 * lh;
            if (lr == 0) sm.e.part2[row * 5 + wnid] = p;
        }
    __syncthreads();
    if (tid < 128) {
        float s = sm.e.part2[tid * 5] + sm.e.part2[tid * 5 + 1] +
                  sm.e.part2[tid * 5 + 2] + sm.e.part2[tid * 5 + 3];
        sm.e.mul[tid] = s * (1.0f / 256.0f);
    }
    __syncthreads();
    // pass 2: variance
#pragma unroll
    for (int mi = 0; mi < 2; mi++)
#pragma unroll
        for (int r = 0; r < 16; r++) {
            int row = wm + mi * 32 + (r & 3) + 8 * (r >> 2) + 4 * lh;
            float m = sm.e.mul[row];
            float d0 = acc[mi][0][r] - m, d1 = acc[mi][1][r] - m;
            float p = d0 * d0 + d1 * d1;
            p += __shfl_xor(p, 1);  p += __shfl_xor(p, 2);
            p += __shfl_xor(p, 4);  p += __shfl_xor(p, 8);
            p += __shfl_xor(p, 16);
            if (lr == 0) sm.e.part2[row * 5 + wnid] = p;
        }
    __syncthreads();
    if (tid < 128) {
        float s = sm.e.part2[tid * 5] + sm.e.part2[tid * 5 + 1] +
                  sm.e.part2[tid * 5 + 2] + sm.e.part2[tid * 5 + 3];
        sm.e.rsl[tid] = rsqrtf(s * (1.0f / 256.0f) + LN_EPS);
    }
    __syncthreads();
    // pass 3: LN affine + GELU + dot w2
#pragma unroll
    for (int mi = 0; mi < 2; mi++)
#pragma unroll
        for (int r = 0; r < 16; r++) {
            int row = wm + mi * 32 + (r & 3) + 8 * (r >> 2) + 4 * lh;
            float m = sm.e.mul[row];
            float rv = sm.e.rsl[row];
            float p = 0.0f;
#pragma unroll
            for (int ni = 0; ni < 2; ni++) {
                float v = (acc[mi][ni][r] - m) * rv * gcol[ni] + becol[ni];
                p += gelu_exact(v) * wcol[ni];
            }
            p += __shfl_xor(p, 1);  p += __shfl_xor(p, 2);
            p += __shfl_xor(p, 4);  p += __shfl_xor(p, 8);
            p += __shfl_xor(p, 16);
            if (lr == 0) sm.e.part2[row * 5 + wnid] = p;
        }
    __syncthreads();
    if (tid < 128) {
        float s = sm.e.part2[tid * 5] + sm.e.part2[tid * 5 + 1] +
                  sm.e.part2[tid * 5 + 2] + sm.e.part2[tid * 5 + 3];
        float logit = s + B2[0];
        float sc = 1.0f / (1.0f + expf(-logit));
        int t = tok0 + tid;
        sc *= (float)MASK[t];
        scf[t] = sc;
        out[O_SCORES + t] = sc;
    }
}

// ---------------- K2: span RLE + top-20 per row ----------------
__global__ __launch_bounds__(1024) void k_spans(
    const float* __restrict__ scf, int* __restrict__ spstart,
    int* __restrict__ splen, float* __restrict__ spavg, int* __restrict__ nsp,
    int* __restrict__ selstart, int* __restrict__ sellen,
    float* __restrict__ selavg, float* __restrict__ selvalid,
    float* __restrict__ out)
{
    const int r = blockIdx.x, tid = threadIdx.x;
    __shared__ float sc[S_LEN];
    __shared__ unsigned char ab[S_LEN];
    __shared__ int scn[1024];
    __shared__ float avgl[2048];
    __shared__ float rv[16];
    __shared__ int ri[16];

    float4 v = ((const float4*)(scf + (size_t)r * S_LEN))[tid];
    const int s0 = tid * 4;
    sc[s0 + 0] = v.x; sc[s0 + 1] = v.y; sc[s0 + 2] = v.z; sc[s0 + 3] = v.w;
    ab[s0 + 0] = (v.x >= THRESH);
    ab[s0 + 1] = (v.y >= THRESH);
    ab[s0 + 2] = (v.z >= THRESH);
    ab[s0 + 3] = (v.w >= THRESH);
    __syncthreads();

    bool st[4];
    int cnt = 0;
#pragma unroll
    for (int i = 0; i < 4; i++) {
        bool a = ab[s0 + i] != 0;
        bool p = (s0 + i == 0) ? false : (ab[s0 + i - 1] != 0);
        st[i] = a && !p;
        cnt += st[i] ? 1 : 0;
    }
    scn[tid] = cnt;
    __syncthreads();
    for (int off = 1; off < 1024; off <<= 1) {
        int mine = scn[tid];
        int add = (tid >= off) ? scn[tid - off] : 0;
        __syncthreads();
        scn[tid] = mine + add;
        __syncthreads();
    }
    const int total = scn[1023];
    int j = scn[tid] - cnt;  // exclusive base
    for (int i = 0; i < 4; i++) {
        if (st[i]) {
            int s = s0 + i;
            float sum = 0.0f;
            int len = 0;
            int e = s;
            while (e < S_LEN && ab[e]) { sum += sc[e]; len++; e++; }
            float avg = sum / (float)len;
            spstart[r * 2048 + j] = s;
            splen[r * 2048 + j] = len;
            spavg[r * 2048 + j] = avg;
            avgl[j] = avg;
            j++;
        }
    }
    if (tid == 0) nsp[r] = total;
    __syncthreads();

    // iterative argmax (tie -> lowest index), exactly lax.top_k order
    for (int k = 0; k < KMAX; k++) {
        float bv = -3.0e38f;
        int bi = 0x7FFFFFFF;
        for (int q = tid; q < total; q += 1024) {
            float a = avgl[q];
            if (a > bv) { bv = a; bi = q; }
        }
#pragma unroll
        for (int m = 1; m < 64; m <<= 1) {
            float ov = __shfl_xor(bv, m);
            int oi = __shfl_xor(bi, m);
            if (ov > bv || (ov == bv && oi < bi)) { bv = ov; bi = oi; }
        }
        if ((tid & 63) == 0) { rv[tid >> 6] = bv; ri[tid >> 6] = bi; }
        __syncthreads();
        if (tid < 64) {
            float v2 = (tid < 16) ? rv[tid] : -3.0e38f;
            int i2 = (tid < 16) ? ri[tid] : 0x7FFFFFFF;
#pragma unroll
            for (int m = 1; m < 16; m <<= 1) {
                float ov = __shfl_xor(v2, m);
                int oi = __shfl_xor(i2, m);
                if (ov > v2 || (ov == v2 && oi < i2)) { v2 = ov; i2 = oi; }
            }
            if (tid == 0) {
                int slot = r * KMAX + k;
                if (k < total) {
                    avgl[i2] = -3.0e38f;
                    int ln = splen[r * 2048 + i2];
                    float vd = (v2 >= THRESH && ln > 0) ? 1.0f : 0.0f;
                    selstart[slot] = spstart[r * 2048 + i2];
                    sellen[slot] = ln;
                    selavg[slot] = v2;
                    selvalid[slot] = vd;
                    out[O_ESC + slot] = v2 * vd;
                    out[O_VALIDK + slot] = vd;
                } else {
                    selstart[slot] = -1;
                    sellen[slot] = 0;
                    selavg[slot] = -1.0f;
                    selvalid[slot] = 0.0f;
                    out[O_ESC + slot] = 0.0f;
                    out[O_VALIDK + slot] = 0.0f;
                }
            }
        }
        __syncthreads();
    }
}

// ---------------- K3: fused tail — pool -> MLP(en) -> MLP(ty) -> type head ----
// one block per slot; entire chain is slot-local
__global__ __launch_bounds__(256) void k_tail(
    const float* __restrict__ X, const int* __restrict__ selstart,
    const int* __restrict__ sellen, const float* __restrict__ selvalid,
    const float* __restrict__ en_w1, const float* __restrict__ en_b1,
    const float* __restrict__ en_g, const float* __restrict__ en_be,
    const float* __restrict__ en_w2, const float* __restrict__ en_b2,
    const float* __restrict__ ty_w1, const float* __restrict__ ty_b1,
    const float* __restrict__ ty_g, const float* __restrict__ ty_be,
    const float* __restrict__ ty_w2, const float* __restrict__ ty_b2,
    float* __restrict__ out)
{
    const int slot = blockIdx.x, tid = threadIdx.x;
    __shared__ float xr[DMODEL];
    __shared__ float g1[HDIM];
    __shared__ float red[8];
    __shared__ float lg[NTYPES];
    const int r = slot / KMAX;
    const int s0 = selstart[slot], ln = sellen[slot];
    const float vd = selvalid[slot];

    // phase 1: mean-pool span rep into xr
    {
        float a0 = 0, a1 = 0, a2 = 0, a3 = 0;
        if (s0 >= 0) {
            const float* base = X + ((size_t)r * S_LEN + s0) * DMODEL;
            for (int t = 0; t < ln; t++) {
                const float* row = base + (size_t)t * DMODEL;
                a0 += row[tid];
                a1 += row[tid + 256];
                a2 += row[tid + 512];
                a3 += row[tid + 768];
            }
        }
        const float dn = (float)((ln > 0) ? ln : 1);
        xr[tid] = a0 / dn * vd;
        xr[tid + 256] = a1 / dn * vd;
        xr[tid + 512] = a2 / dn * vd;
        xr[tid + 768] = a3 / dn * vd;
    }
    __syncthreads();

    // phase 2: enhancer stage-1 (1024->256, LN, GELU) -> g1
    {
        float acc = en_b1[tid];
        const float* wp = en_w1 + tid;
#pragma unroll 16
        for (int k = 0; k < DMODEL; k++) acc += xr[k] * wp[(size_t)k * HDIM];
        float s = acc;
#pragma unroll
        for (int m = 1; m < 64; m <<= 1) s += __shfl_xor(s, m);
        if ((tid & 63) == 0) red[tid >> 6] = s;
        __syncthreads();
        float mu = (red[0] + red[1] + red[2] + red[3]) * (1.0f / 256.0f);
        float d = acc - mu;
        s = d * d;
#pragma unroll
        for (int m = 1; m < 64; m <<= 1) s += __shfl_xor(s, m);
        if ((tid & 63) == 0) red[4 + (tid >> 6)] = s;
        __syncthreads();
        float var = (red[4] + red[5] + red[6] + red[7]) * (1.0f / 256.0f);
        float v = d * rsqrtf(var + LN_EPS) * en_g[tid] + en_be[tid];
        g1[tid] = gelu_exact(v);
    }
    __syncthreads();

    // phase 3: enhancer stage-2 (256->1024), *valid -> out + xr (enhanced)
    {
        float a0 = en_b2[tid], a1 = en_b2[tid + 256],
              a2 = en_b2[tid + 512], a3 = en_b2[tid + 768];
        const float* wp = en_w2 + tid;
#pragma unroll 8
        for (int k = 0; k < HDIM; k++) {
            float g = g1[k];
            const float* w = wp + (size_t)k * DMODEL;
            a0 += g * w[0];
            a1 += g * w[256];
            a2 += g * w[512];
            a3 += g * w[768];
        }
        a0 *= vd; a1 *= vd; a2 *= vd; a3 *= vd;
        const size_t base = (size_t)slot * DMODEL;
        out[O_ENH + base + tid] = a0;
        out[O_ENH + base + tid + 256] = a1;
        out[O_ENH + base + tid + 512] = a2;
        out[O_ENH + base + tid + 768] = a3;
        __syncthreads();   // all g1 reads done before xr overwrite readers sync below
        xr[tid] = a0;
        xr[tid + 256] = a1;
        xr[tid + 512] = a2;
        xr[tid + 768] = a3;
    }
    __syncthreads();

    // phase 4: type stage-1 (1024->256, LN, GELU) -> g1
    {
        float acc = ty_b1[tid];
        const float* wp = ty_w1 + tid;
#pragma unroll 16
        for (int k = 0; k < DMODEL; k++) acc += xr[k] * wp[(size_t)k * HDIM];
        float s = acc;
#pragma unroll
        for (int m = 1; m < 64; m <<= 1) s += __shfl_xor(s, m);
        if ((tid & 63) == 0) red[tid >> 6] = s;
        __syncthreads();
        float mu = (red[0] + red[1] + red[2] + red[3]) * (1.0f / 256.0f);
        float d = acc - mu;
        s = d * d;
#pragma unroll
        for (int m = 1; m < 64; m <<= 1) s += __shfl_xor(s, m);
        if ((tid & 63) == 0) red[4 + (tid >> 6)] = s;
        __syncthreads();
        float var = (red[4] + red[5] + red[6] + red[7]) * (1.0f / 256.0f);
        float v = d * rsqrtf(var + LN_EPS) * ty_g[tid] + ty_be[tid];
        g1[tid] = gelu_exact(v);
    }
    __syncthreads();

    // phase 5: type head (256->8), softmax, argmax
    if (tid < NTYPES) {
        float la = ty_b2[tid];
        for (int k = 0; k < HDIM; k++) la += g1[k] * ty_w2[k * NTYPES + tid];
        lg[tid] = la;
        out[O_TLOG + slot * NTYPES + tid] = la;
    }
    __syncthreads();
    if (tid == 0) {
        float mx = lg[0];
        int am = 0;
        for (int t = 1; t < NTYPES; t++)
            if (lg[t] > mx) { mx = lg[t]; am = t; }  // strict > keeps first max
        float ex[NTYPES], ssum = 0.0f;
        for (int t = 0; t < NTYPES; t++) { ex[t] = expf(lg[t] - mx); ssum += ex[t]; }
        for (int t = 0; t < NTYPES; t++)
            out[O_TPROB + slot * NTYPES + t] = ex[t] / ssum;
        out[O_TYPE + slot] = (float)am;
    }
}

extern "C" void kernel_launch(void* const* d_in, const int* in_sizes, int n_in,
                              void* d_out, int out_size, void* d_ws, size_t ws_size,
                              hipStream_t stream) {
    const float* X = (const float*)d_in[0];
    const int* MASK = (const int*)d_in[1];
    const float* sc_w1 = (const float*)d_in[2];
    const float* sc_b1 = (const float*)d_in[3];
    const float* sc_g  = (const float*)d_in[4];
    const float* sc_be = (const float*)d_in[5];
    const float* sc_w2 = (const float*)d_in[6];
    const float* sc_b2 = (const float*)d_in[7];
    const float* en_w1 = (const float*)d_in[8];
    const float* en_b1 = (const float*)d_in[9];
    const float* en_g  = (const float*)d_in[10];
    const float* en_be = (const float*)d_in[11];
    const float* en_w2 = (const float*)d_in[12];
    const float* en_b2 = (const float*)d_in[13];
    const float* ty_w1 = (const float*)d_in[14];
    const float* ty_b1 = (const float*)d_in[15];
    const float* ty_g  = (const float*)d_in[16];
    const float* ty_be = (const float*)d_in[17];
    const float* ty_w2 = (const float*)d_in[18];
    const float* ty_b2 = (const float*)d_in[19];

    float* out = (float*)d_out;
    float* wsf = (float*)d_ws;
    int* wsi = (int*)d_ws;
    _Float16* w1tc_hi = (_Float16*)(wsf + WS_W1TC_HI);
    _Float16* w1tc_lo = (_Float16*)(wsf + WS_W1TC_LO);

    k_prep<<<32, 256, 0, stream>>>(sc_w1, w1tc_hi, w1tc_lo);
    k_score2<<<256, 512, 0, stream>>>(
        X, w1tc_hi, w1tc_lo, sc_b1, sc_g, sc_be, sc_w2, sc_b2, MASK,
        wsf + WS_SCORES, out);
    k_spans<<<BATCH, 1024, 0, stream>>>(
        wsf + WS_SCORES, wsi + WS_SPSTART, wsi + WS_SPLEN, wsf + WS_SPAVG,
        wsi + WS_NSP, wsi + WS_SELSTART, wsi + WS_SELLEN, wsf + WS_SELAVG,
        wsf + WS_SELVALID, out);
    k_tail<<<NSLOT, 256, 0, stream>>>(
        X, wsi + WS_SELSTART, wsi + WS_SELLEN, wsf + WS_SELVALID,
        en_w1, en_b1, en_g, en_be, en_w2, en_b2,
        ty_w1, ty_b1, ty_g, ty_be, ty_w2, ty_b2, out);
}

// Round 5
// 193.285 us; speedup vs baseline: 1.3164x; 1.3164x over previous
//
#include <hip/hip_runtime.h>
#include <hip/hip_bf16.h>

#define S_LEN 4096
#define BATCH 8
#define DMODEL 1024
#define HDIM 256
#define NTYPES 8
#define KMAX 20
#define NSLOT (BATCH*KMAX)
#define THRESH 0.4f
#define LN_EPS 1e-5f
#define RSQRT2 0.70710678118654752f

// d_out offsets (f32 elements), reference return order
#define O_SCORES 0
#define O_ENH    32768
#define O_TLOG   196608
#define O_ESC    197888
#define O_TPROB  198048
#define O_TYPE   199328
#define O_VALIDK 199488

// ws layout (4-byte units)
#define WS_SCORES   0        // 32768 f32
#define WS_SPSTART  32768    // 16384 i32
#define WS_SPLEN    49152    // 16384 i32
#define WS_SPAVG    65536    // 16384 f32
#define WS_NSP      81920    // 8 i32
#define WS_SELSTART 81936    // 160 i32
#define WS_SELLEN   82096    // 160 i32
#define WS_SELAVG   82256    // 160 f32
#define WS_SELVALID 82416    // 160 f32
// W1 hi/lo f16 image: 32 chunks x 16384 f16 (Bh[8192] || Bl[8192] per chunk),
// laid out as the EXACT LDS byte image (swizzle pre-baked) for global_load_lds.
#define WS_IMG      82576    // 262144 f32 units = 1 MB

typedef _Float16 f16x8 __attribute__((ext_vector_type(8)));
typedef float f32x16 __attribute__((ext_vector_type(16)));

__device__ __forceinline__ float gelu_exact(float v) {
    return 0.5f * v * (1.0f + erff(v * RSQRT2));
}
// swizzle key: spreads fixed-kg fragment reads across LDS 16B-slots
__device__ __forceinline__ int kkey(int r) { return (r ^ (r >> 2)) & 3; }

// async global->LDS, 16 B per lane (dest = wave-uniform base + lane*16)
#define GLL16(g, l) __builtin_amdgcn_global_load_lds( \
    (const __attribute__((address_space(1))) unsigned int*)(g), \
    (__attribute__((address_space(3))) unsigned int*)(l), 16, 0, 0)

// ---------------- K0: W1 -> linear LDS image (hi || lo per chunk) ----------------
// IMG f16 idx: chunk*16384 + [ col*32 + ((j ^ kkey(col))*8) + e ]  (+8192 for lo)
__global__ __launch_bounds__(256) void k_prep(
    const float* __restrict__ W1, _Float16* __restrict__ IMG)
{
    const int c = blockIdx.x;     // k-chunk 0..31
    const int n = threadIdx.x;    // col 0..255
#pragma unroll
    for (int j = 0; j < 4; j++) {
        f16x8 hv, lv;
#pragma unroll
        for (int e = 0; e < 8; e++) {
            float w = W1[(size_t)(c * 32 + j * 8 + e) * HDIM + n];
            _Float16 h = (_Float16)w;
            hv[e] = h;
            lv[e] = (_Float16)(w - (float)h);
        }
        int off = c * 16384 + n * 32 + ((j ^ kkey(n)) * 8);
        *(f16x8*)&IMG[off] = hv;
        *(f16x8*)&IMG[off + 8192] = lv;
    }
}

// ---------------- K1: scorer MLP, 2-phase pipelined split-f16 MFMA ----------------
// 512 blocks x 256 thr (4 waves); tile 64 tok x 256 col; BK=32; wave tile 32x128
__global__ __launch_bounds__(256, 2) void k_score3(
    const float* __restrict__ X, const _Float16* __restrict__ IMG,
    const float* __restrict__ B1, const float* __restrict__ G,
    const float* __restrict__ BE, const float* __restrict__ W2,
    const float* __restrict__ B2, const int* __restrict__ MASK,
    float* __restrict__ scf, float* __restrict__ out)
{
    union SM {
        struct {
            _Float16 A[2][2][2048];   // [buf][hi/lo][row*32 + xor*8]  16 KB
            _Float16 B[2][16384];     // [buf][Bh[8192] || Bl[8192]]   64 KB
        } s;
        struct { float part2[64 * 3]; float mul[64]; float rsl[64]; } e;
    };
    __shared__ SM sm;

    const int tid = threadIdx.x;
    const int lane = tid & 63, wid = tid >> 6;
    const int lr = lane & 31, lh = lane >> 5;
    const int wm = (wid & 1) * 32;       // wave token offset {0,32}
    const int wn = (wid >> 1) * 128;     // wave col offset {0,128}
    const int wg = wid >> 1;
    const int tok0 = blockIdx.x * 64;

    const int arow = tid >> 2, akg = tid & 3;
    const int aoff = arow * 32 + ((akg ^ kkey(arow)) * 8);
    const float* xptr = X + (size_t)(tok0 + arow) * DMODEL + akg * 8;
    const char* gB = (const char*)IMG + wid * 1024 + lane * 16;

    f32x16 acc[4];
#pragma unroll
    for (int ni = 0; ni < 4; ni++) acc[ni] = (f32x16)0.0f;

    // ---- prologue: stage chunk 0 ----
    {
        float4 xa = *(const float4*)xptr;
        float4 xb = *(const float4*)(xptr + 4);
        char* lB = (char*)sm.s.B[0] + wid * 1024;
#pragma unroll
        for (int r = 0; r < 8; r++) GLL16(gB + r * 4096, lB + r * 4096);
        float xv[8] = {xa.x, xa.y, xa.z, xa.w, xb.x, xb.y, xb.z, xb.w};
        f16x8 ah, al;
#pragma unroll
        for (int e = 0; e < 8; e++) {
            _Float16 h = (_Float16)xv[e];
            ah[e] = h;
            al[e] = (_Float16)(xv[e] - (float)h);
        }
        *(f16x8*)&sm.s.A[0][0][aoff] = ah;
        *(f16x8*)&sm.s.A[0][1][aoff] = al;
    }
    __syncthreads();   // drains vmcnt (gll) + lds writes

    int cur = 0;
    for (int c = 0; c < 32; ++c) {
        float4 nxa, nxb;
        // phase A: issue next-chunk loads (overlap with MFMA below)
        if (c < 31) {
            nxa = *(const float4*)(xptr + (c + 1) * 32);
            nxb = *(const float4*)(xptr + (c + 1) * 32 + 4);
            char* lB = (char*)sm.s.B[cur ^ 1] + wid * 1024;
            const char* g = gB + (size_t)(c + 1) * 32768;
#pragma unroll
            for (int r = 0; r < 8; r++) GLL16(g + r * 4096, lB + r * 4096);
        }
        // phase B: compute chunk c from buf cur
        const _Float16* Ah = sm.s.A[cur][0];
        const _Float16* Al = sm.s.A[cur][1];
        const _Float16* Bc = sm.s.B[cur];
#pragma unroll
        for (int s = 0; s < 2; ++s) {
            const int kg = s * 2 + lh;
            const int row = wm + lr;
            const int oa = row * 32 + ((kg ^ kkey(row)) * 8);
            f16x8 fah = *(const f16x8*)&Ah[oa];
            f16x8 fal = *(const f16x8*)&Al[oa];
#pragma unroll
            for (int ni = 0; ni < 4; ni++) {
                const int col = wn + ni * 32 + lr;
                const int ob = col * 32 + ((kg ^ kkey(col)) * 8);
                f16x8 fbh = *(const f16x8*)&Bc[ob];
                f16x8 fbl = *(const f16x8*)&Bc[8192 + ob];
                acc[ni] = __builtin_amdgcn_mfma_f32_32x32x16_f16(fah, fbh, acc[ni], 0, 0, 0);
                acc[ni] = __builtin_amdgcn_mfma_f32_32x32x16_f16(fal, fbh, acc[ni], 0, 0, 0);
                acc[ni] = __builtin_amdgcn_mfma_f32_32x32x16_f16(fah, fbl, acc[ni], 0, 0, 0);
            }
        }
        // phase C: convert & write next A into buf^1 (X regs have arrived under MFMA)
        if (c < 31) {
            float xv[8] = {nxa.x, nxa.y, nxa.z, nxa.w, nxb.x, nxb.y, nxb.z, nxb.w};
            f16x8 ah, al;
#pragma unroll
            for (int e = 0; e < 8; e++) {
                _Float16 h = (_Float16)xv[e];
                ah[e] = h;
                al[e] = (_Float16)(xv[e] - (float)h);
            }
            *(f16x8*)&sm.s.A[cur ^ 1][0][aoff] = ah;
            *(f16x8*)&sm.s.A[cur ^ 1][1][aoff] = al;
        }
        __syncthreads();   // one barrier per chunk: drains gll + lds
        cur ^= 1;
    }

    // ---- epilogue: bias, LN over 256 cols, GELU, dot w2, sigmoid, mask ----
    // C/D: col = wn+ni*32+lr, row = wm+(r&3)+8*(r>>2)+4*lh
    float bcol[4], gcol[4], becol[4], wcol[4];
#pragma unroll
    for (int ni = 0; ni < 4; ni++) {
        int colg = wn + ni * 32 + lr;
        bcol[ni] = B1[colg];
        gcol[ni] = G[colg];
        becol[ni] = BE[colg];
        wcol[ni] = W2[colg];
    }
#pragma unroll
    for (int ni = 0; ni < 4; ni++)
#pragma unroll
        for (int r = 0; r < 16; r++) acc[ni][r] += bcol[ni];

    // pass 1: mean
#pragma unroll
    for (int r = 0; r < 16; r++) {
        float p = acc[0][r] + acc[1][r] + acc[2][r] + acc[3][r];
        p += __shfl_xor(p, 1);  p += __shfl_xor(p, 2);
        p += __shfl_xor(p, 4);  p += __shfl_xor(p, 8);
        p += __shfl_xor(p, 16);
        int row = wm + (r & 3) + 8 * (r >> 2) + 4 * lh;
        if (lr == 0) sm.e.part2[row * 3 + wg] = p;
    }
    __syncthreads();
    if (tid < 64)
        sm.e.mul[tid] = (sm.e.part2[tid * 3] + sm.e.part2[tid * 3 + 1]) * (1.0f / 256.0f);
    __syncthreads();
    // pass 2: variance
#pragma unroll
    for (int r = 0; r < 16; r++) {
        int row = wm + (r & 3) + 8 * (r >> 2) + 4 * lh;
        float m = sm.e.mul[row];
        float p = 0.0f;
#pragma unroll
        for (int ni = 0; ni < 4; ni++) {
            float d = acc[ni][r] - m;
            p += d * d;
        }
        p += __shfl_xor(p, 1);  p += __shfl_xor(p, 2);
        p += __shfl_xor(p, 4);  p += __shfl_xor(p, 8);
        p += __shfl_xor(p, 16);
        if (lr == 0) sm.e.part2[row * 3 + wg] = p;
    }
    __syncthreads();
    if (tid < 64)
        sm.e.rsl[tid] = rsqrtf((sm.e.part2[tid * 3] + sm.e.part2[tid * 3 + 1]) * (1.0f / 256.0f) + LN_EPS);
    __syncthreads();
    // pass 3: LN affine + GELU + dot w2
#pragma unroll
    for (int r = 0; r < 16; r++) {
        int row = wm + (r & 3) + 8 * (r >> 2) + 4 * lh;
        float m = sm.e.mul[row];
        float rv = sm.e.rsl[row];
        float p = 0.0f;
#pragma unroll
        for (int ni = 0; ni < 4; ni++) {
            float v = (acc[ni][r] - m) * rv * gcol[ni] + becol[ni];
            p += gelu_exact(v) * wcol[ni];
        }
        p += __shfl_xor(p, 1);  p += __shfl_xor(p, 2);
        p += __shfl_xor(p, 4);  p += __shfl_xor(p, 8);
        p += __shfl_xor(p, 16);
        if (lr == 0) sm.e.part2[row * 3 + wg] = p;
    }
    __syncthreads();
    if (tid < 64) {
        float s = sm.e.part2[tid * 3] + sm.e.part2[tid * 3 + 1];
        float logit = s + B2[0];
        float sc = 1.0f / (1.0f + expf(-logit));
        int t = tok0 + tid;
        sc *= (float)MASK[t];
        scf[t] = sc;
        out[O_SCORES + t] = sc;
    }
}

// ---------------- K2: span RLE + top-20 per row ----------------
__global__ __launch_bounds__(1024) void k_spans(
    const float* __restrict__ scf, int* __restrict__ spstart,
    int* __restrict__ splen, float* __restrict__ spavg, int* __restrict__ nsp,
    int* __restrict__ selstart, int* __restrict__ sellen,
    float* __restrict__ selavg, float* __restrict__ selvalid,
    float* __restrict__ out)
{
    const int r = blockIdx.x, tid = threadIdx.x;
    __shared__ float sc[S_LEN];
    __shared__ unsigned char ab[S_LEN];
    __shared__ int scn[1024];
    __shared__ float avgl[2048];
    __shared__ float rv[16];
    __shared__ int ri[16];

    float4 v = ((const float4*)(scf + (size_t)r * S_LEN))[tid];
    const int s0 = tid * 4;
    sc[s0 + 0] = v.x; sc[s0 + 1] = v.y; sc[s0 + 2] = v.z; sc[s0 + 3] = v.w;
    ab[s0 + 0] = (v.x >= THRESH);
    ab[s0 + 1] = (v.y >= THRESH);
    ab[s0 + 2] = (v.z >= THRESH);
    ab[s0 + 3] = (v.w >= THRESH);
    __syncthreads();

    bool st[4];
    int cnt = 0;
#pragma unroll
    for (int i = 0; i < 4; i++) {
        bool a = ab[s0 + i] != 0;
        bool p = (s0 + i == 0) ? false : (ab[s0 + i - 1] != 0);
        st[i] = a && !p;
        cnt += st[i] ? 1 : 0;
    }
    scn[tid] = cnt;
    __syncthreads();
    for (int off = 1; off < 1024; off <<= 1) {
        int mine = scn[tid];
        int add = (tid >= off) ? scn[tid - off] : 0;
        __syncthreads();
        scn[tid] = mine + add;
        __syncthreads();
    }
    const int total = scn[1023];
    int j = scn[tid] - cnt;  // exclusive base
    for (int i = 0; i < 4; i++) {
        if (st[i]) {
            int s = s0 + i;
            float sum = 0.0f;
            int len = 0;
            int e = s;
            while (e < S_LEN && ab[e]) { sum += sc[e]; len++; e++; }
            float avg = sum / (float)len;
            spstart[r * 2048 + j] = s;
            splen[r * 2048 + j] = len;
            spavg[r * 2048 + j] = avg;
            avgl[j] = avg;
            j++;
        }
    }
    if (tid == 0) nsp[r] = total;
    __syncthreads();

    // iterative argmax (tie -> lowest index), exactly lax.top_k order
    for (int k = 0; k < KMAX; k++) {
        float bv = -3.0e38f;
        int bi = 0x7FFFFFFF;
        for (int q = tid; q < total; q += 1024) {
            float a = avgl[q];
            if (a > bv) { bv = a; bi = q; }
        }
#pragma unroll
        for (int m = 1; m < 64; m <<= 1) {
            float ov = __shfl_xor(bv, m);
            int oi = __shfl_xor(bi, m);
            if (ov > bv || (ov == bv && oi < bi)) { bv = ov; bi = oi; }
        }
        if ((tid & 63) == 0) { rv[tid >> 6] = bv; ri[tid >> 6] = bi; }
        __syncthreads();
        if (tid < 64) {
            float v2 = (tid < 16) ? rv[tid] : -3.0e38f;
            int i2 = (tid < 16) ? ri[tid] : 0x7FFFFFFF;
#pragma unroll
            for (int m = 1; m < 16; m <<= 1) {
                float ov = __shfl_xor(v2, m);
                int oi = __shfl_xor(i2, m);
                if (ov > v2 || (ov == v2 && oi < i2)) { v2 = ov; i2 = oi; }
            }
            if (tid == 0) {
                int slot = r * KMAX + k;
                if (k < total) {
                    avgl[i2] = -3.0e38f;
                    int ln = splen[r * 2048 + i2];
                    float vd = (v2 >= THRESH && ln > 0) ? 1.0f : 0.0f;
                    selstart[slot] = spstart[r * 2048 + i2];
                    sellen[slot] = ln;
                    selavg[slot] = v2;
                    selvalid[slot] = vd;
                    out[O_ESC + slot] = v2 * vd;
                    out[O_VALIDK + slot] = vd;
                } else {
                    selstart[slot] = -1;
                    sellen[slot] = 0;
                    selavg[slot] = -1.0f;
                    selvalid[slot] = 0.0f;
                    out[O_ESC + slot] = 0.0f;
                    out[O_VALIDK + slot] = 0.0f;
                }
            }
        }
        __syncthreads();
    }
}

// ---------------- K3: fused tail — pool -> MLP(en) -> MLP(ty) -> type head ----
__global__ __launch_bounds__(256) void k_tail(
    const float* __restrict__ X, const int* __restrict__ selstart,
    const int* __restrict__ sellen, const float* __restrict__ selvalid,
    const float* __restrict__ en_w1, const float* __restrict__ en_b1,
    const float* __restrict__ en_g, const float* __restrict__ en_be,
    const float* __restrict__ en_w2, const float* __restrict__ en_b2,
    const float* __restrict__ ty_w1, const float* __restrict__ ty_b1,
    const float* __restrict__ ty_g, const float* __restrict__ ty_be,
    const float* __restrict__ ty_w2, const float* __restrict__ ty_b2,
    float* __restrict__ out)
{
    const int slot = blockIdx.x, tid = threadIdx.x;
    __shared__ float xr[DMODEL];
    __shared__ float g1[HDIM];
    __shared__ float red[8];
    __shared__ float lg[NTYPES];
    const int r = slot / KMAX;
    const int s0 = selstart[slot], ln = sellen[slot];
    const float vd = selvalid[slot];

    {
        float a0 = 0, a1 = 0, a2 = 0, a3 = 0;
        if (s0 >= 0) {
            const float* base = X + ((size_t)r * S_LEN + s0) * DMODEL;
            for (int t = 0; t < ln; t++) {
                const float* row = base + (size_t)t * DMODEL;
                a0 += row[tid];
                a1 += row[tid + 256];
                a2 += row[tid + 512];
                a3 += row[tid + 768];
            }
        }
        const float dn = (float)((ln > 0) ? ln : 1);
        xr[tid] = a0 / dn * vd;
        xr[tid + 256] = a1 / dn * vd;
        xr[tid + 512] = a2 / dn * vd;
        xr[tid + 768] = a3 / dn * vd;
    }
    __syncthreads();

    {
        float acc = en_b1[tid];
        const float* wp = en_w1 + tid;
#pragma unroll 16
        for (int k = 0; k < DMODEL; k++) acc += xr[k] * wp[(size_t)k * HDIM];
        float s = acc;
#pragma unroll
        for (int m = 1; m < 64; m <<= 1) s += __shfl_xor(s, m);
        if ((tid & 63) == 0) red[tid >> 6] = s;
        __syncthreads();
        float mu = (red[0] + red[1] + red[2] + red[3]) * (1.0f / 256.0f);
        float d = acc - mu;
        s = d * d;
#pragma unroll
        for (int m = 1; m < 64; m <<= 1) s += __shfl_xor(s, m);
        if ((tid & 63) == 0) red[4 + (tid >> 6)] = s;
        __syncthreads();
        float var = (red[4] + red[5] + red[6] + red[7]) * (1.0f / 256.0f);
        float v = d * rsqrtf(var + LN_EPS) * en_g[tid] + en_be[tid];
        g1[tid] = gelu_exact(v);
    }
    __syncthreads();

    {
        float a0 = en_b2[tid], a1 = en_b2[tid + 256],
              a2 = en_b2[tid + 512], a3 = en_b2[tid + 768];
        const float* wp = en_w2 + tid;
#pragma unroll 8
        for (int k = 0; k < HDIM; k++) {
            float g = g1[k];
            const float* w = wp + (size_t)k * DMODEL;
            a0 += g * w[0];
            a1 += g * w[256];
            a2 += g * w[512];
            a3 += g * w[768];
        }
        a0 *= vd; a1 *= vd; a2 *= vd; a3 *= vd;
        const size_t base = (size_t)slot * DMODEL;
        out[O_ENH + base + tid] = a0;
        out[O_ENH + base + tid + 256] = a1;
        out[O_ENH + base + tid + 512] = a2;
        out[O_ENH + base + tid + 768] = a3;
        __syncthreads();
        xr[tid] = a0;
        xr[tid + 256] = a1;
        xr[tid + 512] = a2;
        xr[tid + 768] = a3;
    }
    __syncthreads();

    {
        float acc = ty_b1[tid];
        const float* wp = ty_w1 + tid;
#pragma unroll 16
        for (int k = 0; k < DMODEL; k++) acc += xr[k] * wp[(size_t)k * HDIM];
        float s = acc;
#pragma unroll
        for (int m = 1; m < 64; m <<= 1) s += __shfl_xor(s, m);
        if ((tid & 63) == 0) red[tid >> 6] = s;
        __syncthreads();
        float mu = (red[0] + red[1] + red[2] + red[3]) * (1.0f / 256.0f);
        float d = acc - mu;
        s = d * d;
#pragma unroll
        for (int m = 1; m < 64; m <<= 1) s += __shfl_xor(s, m);
        if ((tid & 63) == 0) red[4 + (tid >> 6)] = s;
        __syncthreads();
        float var = (red[4] + red[5] + red[6] + red[7]) * (1.0f / 256.0f);
        float v = d * rsqrtf(var + LN_EPS) * ty_g[tid] + ty_be[tid];
        g1[tid] = gelu_exact(v);
    }
    __syncthreads();

    if (tid < NTYPES) {
        float la = ty_b2[tid];
        for (int k = 0; k < HDIM; k++) la += g1[k] * ty_w2[k * NTYPES + tid];
        lg[tid] = la;
        out[O_TLOG + slot * NTYPES + tid] = la;
    }
    __syncthreads();
    if (tid == 0) {
        float mx = lg[0];
        int am = 0;
        for (int t = 1; t < NTYPES; t++)
            if (lg[t] > mx) { mx = lg[t]; am = t; }
        float ex[NTYPES], ssum = 0.0f;
        for (int t = 0; t < NTYPES; t++) { ex[t] = expf(lg[t] - mx); ssum += ex[t]; }
        for (int t = 0; t < NTYPES; t++)
            out[O_TPROB + slot * NTYPES + t] = ex[t] / ssum;
        out[O_TYPE + slot] = (float)am;
    }
}

extern "C" void kernel_launch(void* const* d_in, const int* in_sizes, int n_in,
                              void* d_out, int out_size, void* d_ws, size_t ws_size,
                              hipStream_t stream) {
    const float* X = (const float*)d_in[0];
    const int* MASK = (const int*)d_in[1];
    const float* sc_w1 = (const float*)d_in[2];
    const float* sc_b1 = (const float*)d_in[3];
    const float* sc_g  = (const float*)d_in[4];
    const float* sc_be = (const float*)d_in[5];
    const float* sc_w2 = (const float*)d_in[6];
    const float* sc_b2 = (const float*)d_in[7];
    const float* en_w1 = (const float*)d_in[8];
    const float* en_b1 = (const float*)d_in[9];
    const float* en_g  = (const float*)d_in[10];
    const float* en_be = (const float*)d_in[11];
    const float* en_w2 = (const float*)d_in[12];
    const float* en_b2 = (const float*)d_in[13];
    const float* ty_w1 = (const float*)d_in[14];
    const float* ty_b1 = (const float*)d_in[15];
    const float* ty_g  = (const float*)d_in[16];
    const float* ty_be = (const float*)d_in[17];
    const float* ty_w2 = (const float*)d_in[18];
    const float* ty_b2 = (const float*)d_in[19];

    float* out = (float*)d_out;
    float* wsf = (float*)d_ws;
    int* wsi = (int*)d_ws;
    _Float16* img = (_Float16*)(wsf + WS_IMG);

    k_prep<<<32, 256, 0, stream>>>(sc_w1, img);
    k_score3<<<(BATCH * S_LEN) / 64, 256, 0, stream>>>(
        X, img, sc_b1, sc_g, sc_be, sc_w2, sc_b2, MASK, wsf + WS_SCORES, out);
    k_spans<<<BATCH, 1024, 0, stream>>>(
        wsf + WS_SCORES, wsi + WS_SPSTART, wsi + WS_SPLEN, wsf + WS_SPAVG,
        wsi + WS_NSP, wsi + WS_SELSTART, wsi + WS_SELLEN, wsf + WS_SELAVG,
        wsf + WS_SELVALID, out);
    k_tail<<<NSLOT, 256, 0, stream>>>(
        X, wsi + WS_SELSTART, wsi + WS_SELLEN, wsf + WS_SELVALID,
        en_w1, en_b1, en_g, en_be, en_w2, en_b2,
        ty_w1, ty_b1, ty_g, ty_be, ty_w2, ty_b2, out);
}

// Round 6
// 155.680 us; speedup vs baseline: 1.6344x; 1.2416x over previous
//
#include <hip/hip_runtime.h>
#include <hip/hip_bf16.h>

#define S_LEN 4096
#define BATCH 8
#define DMODEL 1024
#define HDIM 256
#define NTYPES 8
#define KMAX 20
#define NSLOT (BATCH*KMAX)
#define THRESH 0.4f
#define LN_EPS 1e-5f
#define RSQRT2 0.70710678118654752f

// d_out offsets (f32 elements), reference return order
#define O_SCORES 0
#define O_ENH    32768
#define O_TLOG   196608
#define O_ESC    197888
#define O_TPROB  198048
#define O_TYPE   199328
#define O_VALIDK 199488

// ws layout (4-byte units)
#define WS_SCORES   0        // 32768 f32
#define WS_SPSTART  32768    // 16384 i32
#define WS_SPLEN    49152    // 16384 i32
#define WS_SPAVG    65536    // 16384 f32
#define WS_NSP      81920    // 8 i32
#define WS_SELSTART 81936    // 160 i32
#define WS_SELLEN   82096    // 160 i32
#define WS_SELAVG   82256    // 160 f32
#define WS_SELVALID 82416    // 160 f32
// W1 hi/lo f16 image: 32 chunks x 16384 f16 (Bh[8192] || Bl[8192] per chunk),
// laid out as the EXACT LDS byte image (swizzle pre-baked) for global_load_lds.
#define WS_IMG      82576    // 262144 f32 units = 1 MB

typedef _Float16 f16x8 __attribute__((ext_vector_type(8)));
typedef float f32x16 __attribute__((ext_vector_type(16)));

__device__ __forceinline__ float gelu_exact(float v) {
    return 0.5f * v * (1.0f + erff(v * RSQRT2));
}
// swizzle key: spreads fixed-kg fragment reads across LDS 16B-slots
__device__ __forceinline__ int kkey(int r) { return (r ^ (r >> 2)) & 3; }

// async global->LDS, 16 B per lane (dest = wave-uniform base + lane*16)
#define GLL16(g, l) __builtin_amdgcn_global_load_lds( \
    (const __attribute__((address_space(1))) unsigned int*)(g), \
    (__attribute__((address_space(3))) unsigned int*)(l), 16, 0, 0)

// ---------------- K0: W1 -> linear LDS image (hi || lo per chunk) ----------------
__global__ __launch_bounds__(256) void k_prep(
    const float* __restrict__ W1, _Float16* __restrict__ IMG)
{
    const int c = blockIdx.x;     // k-chunk 0..31
    const int n = threadIdx.x;    // col 0..255
#pragma unroll
    for (int j = 0; j < 4; j++) {
        f16x8 hv, lv;
#pragma unroll
        for (int e = 0; e < 8; e++) {
            float w = W1[(size_t)(c * 32 + j * 8 + e) * HDIM + n];
            _Float16 h = (_Float16)w;
            hv[e] = h;
            lv[e] = (_Float16)(w - (float)h);
        }
        int off = c * 16384 + n * 32 + ((j ^ kkey(n)) * 8);
        *(f16x8*)&IMG[off] = hv;
        *(f16x8*)&IMG[off + 8192] = lv;
    }
}

// ---------------- K1: scorer MLP, 2-phase pipelined split-f16 MFMA ----------------
__global__ __launch_bounds__(256, 2) void k_score3(
    const float* __restrict__ X, const _Float16* __restrict__ IMG,
    const float* __restrict__ B1, const float* __restrict__ G,
    const float* __restrict__ BE, const float* __restrict__ W2,
    const float* __restrict__ B2, const int* __restrict__ MASK,
    float* __restrict__ scf, float* __restrict__ out)
{
    union SM {
        struct {
            _Float16 A[2][2][2048];   // [buf][hi/lo][row*32 + xor*8]  16 KB
            _Float16 B[2][16384];     // [buf][Bh[8192] || Bl[8192]]   64 KB
        } s;
        struct { float part2[64 * 3]; float mul[64]; float rsl[64]; } e;
    };
    __shared__ SM sm;

    const int tid = threadIdx.x;
    const int lane = tid & 63, wid = tid >> 6;
    const int lr = lane & 31, lh = lane >> 5;
    const int wm = (wid & 1) * 32;
    const int wn = (wid >> 1) * 128;
    const int wg = wid >> 1;
    const int tok0 = blockIdx.x * 64;

    const int arow = tid >> 2, akg = tid & 3;
    const int aoff = arow * 32 + ((akg ^ kkey(arow)) * 8);
    const float* xptr = X + (size_t)(tok0 + arow) * DMODEL + akg * 8;
    const char* gB = (const char*)IMG + wid * 1024 + lane * 16;

    f32x16 acc[4];
#pragma unroll
    for (int ni = 0; ni < 4; ni++) acc[ni] = (f32x16)0.0f;

    {
        float4 xa = *(const float4*)xptr;
        float4 xb = *(const float4*)(xptr + 4);
        char* lB = (char*)sm.s.B[0] + wid * 1024;
#pragma unroll
        for (int r = 0; r < 8; r++) GLL16(gB + r * 4096, lB + r * 4096);
        float xv[8] = {xa.x, xa.y, xa.z, xa.w, xb.x, xb.y, xb.z, xb.w};
        f16x8 ah, al;
#pragma unroll
        for (int e = 0; e < 8; e++) {
            _Float16 h = (_Float16)xv[e];
            ah[e] = h;
            al[e] = (_Float16)(xv[e] - (float)h);
        }
        *(f16x8*)&sm.s.A[0][0][aoff] = ah;
        *(f16x8*)&sm.s.A[0][1][aoff] = al;
    }
    __syncthreads();

    int cur = 0;
    for (int c = 0; c < 32; ++c) {
        float4 nxa, nxb;
        if (c < 31) {
            nxa = *(const float4*)(xptr + (c + 1) * 32);
            nxb = *(const float4*)(xptr + (c + 1) * 32 + 4);
            char* lB = (char*)sm.s.B[cur ^ 1] + wid * 1024;
            const char* g = gB + (size_t)(c + 1) * 32768;
#pragma unroll
            for (int r = 0; r < 8; r++) GLL16(g + r * 4096, lB + r * 4096);
        }
        const _Float16* Ah = sm.s.A[cur][0];
        const _Float16* Al = sm.s.A[cur][1];
        const _Float16* Bc = sm.s.B[cur];
#pragma unroll
        for (int s = 0; s < 2; ++s) {
            const int kg = s * 2 + lh;
            const int row = wm + lr;
            const int oa = row * 32 + ((kg ^ kkey(row)) * 8);
            f16x8 fah = *(const f16x8*)&Ah[oa];
            f16x8 fal = *(const f16x8*)&Al[oa];
#pragma unroll
            for (int ni = 0; ni < 4; ni++) {
                const int col = wn + ni * 32 + lr;
                const int ob = col * 32 + ((kg ^ kkey(col)) * 8);
                f16x8 fbh = *(const f16x8*)&Bc[ob];
                f16x8 fbl = *(const f16x8*)&Bc[8192 + ob];
                acc[ni] = __builtin_amdgcn_mfma_f32_32x32x16_f16(fah, fbh, acc[ni], 0, 0, 0);
                acc[ni] = __builtin_amdgcn_mfma_f32_32x32x16_f16(fal, fbh, acc[ni], 0, 0, 0);
                acc[ni] = __builtin_amdgcn_mfma_f32_32x32x16_f16(fah, fbl, acc[ni], 0, 0, 0);
            }
        }
        if (c < 31) {
            float xv[8] = {nxa.x, nxa.y, nxa.z, nxa.w, nxb.x, nxb.y, nxb.z, nxb.w};
            f16x8 ah, al;
#pragma unroll
            for (int e = 0; e < 8; e++) {
                _Float16 h = (_Float16)xv[e];
                ah[e] = h;
                al[e] = (_Float16)(xv[e] - (float)h);
            }
            *(f16x8*)&sm.s.A[cur ^ 1][0][aoff] = ah;
            *(f16x8*)&sm.s.A[cur ^ 1][1][aoff] = al;
        }
        __syncthreads();
        cur ^= 1;
    }

    // epilogue: bias, LN, GELU, dot w2, sigmoid, mask
    float bcol[4], gcol[4], becol[4], wcol[4];
#pragma unroll
    for (int ni = 0; ni < 4; ni++) {
        int colg = wn + ni * 32 + lr;
        bcol[ni] = B1[colg];
        gcol[ni] = G[colg];
        becol[ni] = BE[colg];
        wcol[ni] = W2[colg];
    }
#pragma unroll
    for (int ni = 0; ni < 4; ni++)
#pragma unroll
        for (int r = 0; r < 16; r++) acc[ni][r] += bcol[ni];

#pragma unroll
    for (int r = 0; r < 16; r++) {
        float p = acc[0][r] + acc[1][r] + acc[2][r] + acc[3][r];
        p += __shfl_xor(p, 1);  p += __shfl_xor(p, 2);
        p += __shfl_xor(p, 4);  p += __shfl_xor(p, 8);
        p += __shfl_xor(p, 16);
        int row = wm + (r & 3) + 8 * (r >> 2) + 4 * lh;
        if (lr == 0) sm.e.part2[row * 3 + wg] = p;
    }
    __syncthreads();
    if (tid < 64)
        sm.e.mul[tid] = (sm.e.part2[tid * 3] + sm.e.part2[tid * 3 + 1]) * (1.0f / 256.0f);
    __syncthreads();
#pragma unroll
    for (int r = 0; r < 16; r++) {
        int row = wm + (r & 3) + 8 * (r >> 2) + 4 * lh;
        float m = sm.e.mul[row];
        float p = 0.0f;
#pragma unroll
        for (int ni = 0; ni < 4; ni++) {
            float d = acc[ni][r] - m;
            p += d * d;
        }
        p += __shfl_xor(p, 1);  p += __shfl_xor(p, 2);
        p += __shfl_xor(p, 4);  p += __shfl_xor(p, 8);
        p += __shfl_xor(p, 16);
        if (lr == 0) sm.e.part2[row * 3 + wg] = p;
    }
    __syncthreads();
    if (tid < 64)
        sm.e.rsl[tid] = rsqrtf((sm.e.part2[tid * 3] + sm.e.part2[tid * 3 + 1]) * (1.0f / 256.0f) + LN_EPS);
    __syncthreads();
#pragma unroll
    for (int r = 0; r < 16; r++) {
        int row = wm + (r & 3) + 8 * (r >> 2) + 4 * lh;
        float m = sm.e.mul[row];
        float rv = sm.e.rsl[row];
        float p = 0.0f;
#pragma unroll
        for (int ni = 0; ni < 4; ni++) {
            float v = (acc[ni][r] - m) * rv * gcol[ni] + becol[ni];
            p += gelu_exact(v) * wcol[ni];
        }
        p += __shfl_xor(p, 1);  p += __shfl_xor(p, 2);
        p += __shfl_xor(p, 4);  p += __shfl_xor(p, 8);
        p += __shfl_xor(p, 16);
        if (lr == 0) sm.e.part2[row * 3 + wg] = p;
    }
    __syncthreads();
    if (tid < 64) {
        float s = sm.e.part2[tid * 3] + sm.e.part2[tid * 3 + 1];
        float logit = s + B2[0];
        float sc = 1.0f / (1.0f + expf(-logit));
        int t = tok0 + tid;
        sc *= (float)MASK[t];
        scf[t] = sc;
        out[O_SCORES + t] = sc;
    }
}

// ---------------- K2: span RLE + top-20 per row ----------------
__global__ __launch_bounds__(1024) void k_spans(
    const float* __restrict__ scf, int* __restrict__ spstart,
    int* __restrict__ splen, float* __restrict__ spavg, int* __restrict__ nsp,
    int* __restrict__ selstart, int* __restrict__ sellen,
    float* __restrict__ selavg, float* __restrict__ selvalid,
    float* __restrict__ out)
{
    const int r = blockIdx.x, tid = threadIdx.x;
    __shared__ float sc[S_LEN];
    __shared__ unsigned char ab[S_LEN];
    __shared__ int scn[1024];
    __shared__ float avgl[2048];
    __shared__ float rv[16];
    __shared__ int ri[16];

    float4 v = ((const float4*)(scf + (size_t)r * S_LEN))[tid];
    const int s0 = tid * 4;
    sc[s0 + 0] = v.x; sc[s0 + 1] = v.y; sc[s0 + 2] = v.z; sc[s0 + 3] = v.w;
    ab[s0 + 0] = (v.x >= THRESH);
    ab[s0 + 1] = (v.y >= THRESH);
    ab[s0 + 2] = (v.z >= THRESH);
    ab[s0 + 3] = (v.w >= THRESH);
    __syncthreads();

    bool st[4];
    int cnt = 0;
#pragma unroll
    for (int i = 0; i < 4; i++) {
        bool a = ab[s0 + i] != 0;
        bool p = (s0 + i == 0) ? false : (ab[s0 + i - 1] != 0);
        st[i] = a && !p;
        cnt += st[i] ? 1 : 0;
    }
    scn[tid] = cnt;
    __syncthreads();
    for (int off = 1; off < 1024; off <<= 1) {
        int mine = scn[tid];
        int add = (tid >= off) ? scn[tid - off] : 0;
        __syncthreads();
        scn[tid] = mine + add;
        __syncthreads();
    }
    const int total = scn[1023];
    int j = scn[tid] - cnt;
    for (int i = 0; i < 4; i++) {
        if (st[i]) {
            int s = s0 + i;
            float sum = 0.0f;
            int len = 0;
            int e = s;
            while (e < S_LEN && ab[e]) { sum += sc[e]; len++; e++; }
            float avg = sum / (float)len;
            spstart[r * 2048 + j] = s;
            splen[r * 2048 + j] = len;
            spavg[r * 2048 + j] = avg;
            avgl[j] = avg;
            j++;
        }
    }
    if (tid == 0) nsp[r] = total;
    __syncthreads();

    for (int k = 0; k < KMAX; k++) {
        float bv = -3.0e38f;
        int bi = 0x7FFFFFFF;
        for (int q = tid; q < total; q += 1024) {
            float a = avgl[q];
            if (a > bv) { bv = a; bi = q; }
        }
#pragma unroll
        for (int m = 1; m < 64; m <<= 1) {
            float ov = __shfl_xor(bv, m);
            int oi = __shfl_xor(bi, m);
            if (ov > bv || (ov == bv && oi < bi)) { bv = ov; bi = oi; }
        }
        if ((tid & 63) == 0) { rv[tid >> 6] = bv; ri[tid >> 6] = bi; }
        __syncthreads();
        if (tid < 64) {
            float v2 = (tid < 16) ? rv[tid] : -3.0e38f;
            int i2 = (tid < 16) ? ri[tid] : 0x7FFFFFFF;
#pragma unroll
            for (int m = 1; m < 16; m <<= 1) {
                float ov = __shfl_xor(v2, m);
                int oi = __shfl_xor(i2, m);
                if (ov > v2 || (ov == v2 && oi < i2)) { v2 = ov; i2 = oi; }
            }
            if (tid == 0) {
                int slot = r * KMAX + k;
                if (k < total) {
                    avgl[i2] = -3.0e38f;
                    int ln = splen[r * 2048 + i2];
                    float vd = (v2 >= THRESH && ln > 0) ? 1.0f : 0.0f;
                    selstart[slot] = spstart[r * 2048 + i2];
                    sellen[slot] = ln;
                    selavg[slot] = v2;
                    selvalid[slot] = vd;
                    out[O_ESC + slot] = v2 * vd;
                    out[O_VALIDK + slot] = vd;
                } else {
                    selstart[slot] = -1;
                    sellen[slot] = 0;
                    selavg[slot] = -1.0f;
                    selvalid[slot] = 0.0f;
                    out[O_ESC + slot] = 0.0f;
                    out[O_VALIDK + slot] = 0.0f;
                }
            }
        }
        __syncthreads();
    }
}

// ---------------- K3: fused tail, 1024 threads (16 waves, 4/SIMD) ----------------
// stage-1 GEMVs use 4-way K-split; type head uses parallel 256-thread reduce.
__global__ __launch_bounds__(1024) void k_tail2(
    const float* __restrict__ X, const int* __restrict__ selstart,
    const int* __restrict__ sellen, const float* __restrict__ selvalid,
    const float* __restrict__ en_w1, const float* __restrict__ en_b1,
    const float* __restrict__ en_g, const float* __restrict__ en_be,
    const float* __restrict__ en_w2, const float* __restrict__ en_b2,
    const float* __restrict__ ty_w1, const float* __restrict__ ty_b1,
    const float* __restrict__ ty_g, const float* __restrict__ ty_be,
    const float* __restrict__ ty_w2, const float* __restrict__ ty_b2,
    float* __restrict__ out)
{
    const int slot = blockIdx.x, tid = threadIdx.x;
    __shared__ float xr[DMODEL];   // pooled rep / enhanced
    __shared__ float ps[DMODEL];   // stage-1 K-split partials
    __shared__ float g1[HDIM];
    __shared__ float red[8];
    __shared__ float lgp[4 * NTYPES];
    __shared__ float lg[NTYPES];

    const int r = slot / KMAX;
    const int s0 = selstart[slot], ln = sellen[slot];
    const float vd = selvalid[slot];
    const int j = tid & 255, p = tid >> 8;   // stage-1 coords

    // phase 1: mean-pool (one dim per thread)
    {
        float a = 0.0f;
        if (s0 >= 0) {
            const float* base = X + ((size_t)r * S_LEN + s0) * DMODEL + tid;
#pragma unroll 4
            for (int t = 0; t < ln; t++) a += base[(size_t)t * DMODEL];
        }
        const float dn = (ln > 0) ? (float)ln : 1.0f;
        xr[tid] = a / dn * vd;
    }
    __syncthreads();

    // phase 2: enhancer stage-1 (1024->256), 4-way K-split, LN, GELU
    {
        float acc = 0.0f;
        const float* wp = en_w1 + (size_t)(p * 256) * HDIM + j;
        const float* xp = xr + p * 256;
#pragma unroll 16
        for (int k = 0; k < 256; k++) acc += xp[k] * wp[(size_t)k * HDIM];
        ps[tid] = acc;
    }
    __syncthreads();
    float h = 0.0f, mu = 0.0f;
    if (tid < 256) {
        h = ps[tid] + ps[256 + tid] + ps[512 + tid] + ps[768 + tid] + en_b1[tid];
        float s = h;
#pragma unroll
        for (int m = 1; m < 64; m <<= 1) s += __shfl_xor(s, m);
        if ((tid & 63) == 0) red[tid >> 6] = s;
    }
    __syncthreads();
    if (tid < 256) {
        mu = (red[0] + red[1] + red[2] + red[3]) * (1.0f / 256.0f);
        float d = h - mu;
        float s = d * d;
#pragma unroll
        for (int m = 1; m < 64; m <<= 1) s += __shfl_xor(s, m);
        if ((tid & 63) == 0) red[4 + (tid >> 6)] = s;
    }
    __syncthreads();
    if (tid < 256) {
        float var = (red[4] + red[5] + red[6] + red[7]) * (1.0f / 256.0f);
        float v = (h - mu) * rsqrtf(var + LN_EPS) * en_g[tid] + en_be[tid];
        g1[tid] = gelu_exact(v);
    }
    __syncthreads();

    // phase 3: enhancer stage-2 (256->1024), *valid -> out + xr
    {
        float acc = en_b2[tid];
        const float* wp = en_w2 + tid;
#pragma unroll 16
        for (int k = 0; k < 256; k++) acc += g1[k] * wp[(size_t)k * DMODEL];
        acc *= vd;
        out[O_ENH + (size_t)slot * DMODEL + tid] = acc;
        xr[tid] = acc;
    }
    __syncthreads();

    // phase 4: type stage-1 (1024->256), 4-way K-split, LN, GELU
    {
        float acc = 0.0f;
        const float* wp = ty_w1 + (size_t)(p * 256) * HDIM + j;
        const float* xp = xr + p * 256;
#pragma unroll 16
        for (int k = 0; k < 256; k++) acc += xp[k] * wp[(size_t)k * HDIM];
        ps[tid] = acc;
    }
    __syncthreads();
    h = 0.0f; mu = 0.0f;
    if (tid < 256) {
        h = ps[tid] + ps[256 + tid] + ps[512 + tid] + ps[768 + tid] + ty_b1[tid];
        float s = h;
#pragma unroll
        for (int m = 1; m < 64; m <<= 1) s += __shfl_xor(s, m);
        if ((tid & 63) == 0) red[tid >> 6] = s;
    }
    __syncthreads();
    if (tid < 256) {
        mu = (red[0] + red[1] + red[2] + red[3]) * (1.0f / 256.0f);
        float d = h - mu;
        float s = d * d;
#pragma unroll
        for (int m = 1; m < 64; m <<= 1) s += __shfl_xor(s, m);
        if ((tid & 63) == 0) red[4 + (tid >> 6)] = s;
    }
    __syncthreads();
    if (tid < 256) {
        float var = (red[4] + red[5] + red[6] + red[7]) * (1.0f / 256.0f);
        float v = (h - mu) * rsqrtf(var + LN_EPS) * ty_g[tid] + ty_be[tid];
        g1[tid] = gelu_exact(v);
    }
    __syncthreads();

    // phase 5: type head (256->8), parallel reduce + softmax + argmax
    if (tid < 256) {
        float gv = g1[tid];
        float4 w0 = *(const float4*)&ty_w2[tid * NTYPES];
        float4 w1v = *(const float4*)&ty_w2[tid * NTYPES + 4];
        float pj[8] = {gv * w0.x, gv * w0.y, gv * w0.z, gv * w0.w,
                       gv * w1v.x, gv * w1v.y, gv * w1v.z, gv * w1v.w};
#pragma unroll
        for (int q = 0; q < 8; q++) {
            float s = pj[q];
#pragma unroll
            for (int m = 1; m < 64; m <<= 1) s += __shfl_xor(s, m);
            pj[q] = s;
        }
        if ((tid & 63) == 0) {
#pragma unroll
            for (int q = 0; q < 8; q++) lgp[(tid >> 6) * NTYPES + q] = pj[q];
        }
    }
    __syncthreads();
    if (tid < NTYPES) {
        float la = ty_b2[tid] + lgp[tid] + lgp[NTYPES + tid] +
                   lgp[2 * NTYPES + tid] + lgp[3 * NTYPES + tid];
        lg[tid] = la;
        out[O_TLOG + slot * NTYPES + tid] = la;
    }
    __syncthreads();
    if (tid == 0) {
        float mx = lg[0];
        int am = 0;
        for (int t = 1; t < NTYPES; t++)
            if (lg[t] > mx) { mx = lg[t]; am = t; }
        float ex[NTYPES], ssum = 0.0f;
        for (int t = 0; t < NTYPES; t++) { ex[t] = expf(lg[t] - mx); ssum += ex[t]; }
        for (int t = 0; t < NTYPES; t++)
            out[O_TPROB + slot * NTYPES + t] = ex[t] / ssum;
        out[O_TYPE + slot] = (float)am;
    }
}

extern "C" void kernel_launch(void* const* d_in, const int* in_sizes, int n_in,
                              void* d_out, int out_size, void* d_ws, size_t ws_size,
                              hipStream_t stream) {
    const float* X = (const float*)d_in[0];
    const int* MASK = (const int*)d_in[1];
    const float* sc_w1 = (const float*)d_in[2];
    const float* sc_b1 = (const float*)d_in[3];
    const float* sc_g  = (const float*)d_in[4];
    const float* sc_be = (const float*)d_in[5];
    const float* sc_w2 = (const float*)d_in[6];
    const float* sc_b2 = (const float*)d_in[7];
    const float* en_w1 = (const float*)d_in[8];
    const float* en_b1 = (const float*)d_in[9];
    const float* en_g  = (const float*)d_in[10];
    const float* en_be = (const float*)d_in[11];
    const float* en_w2 = (const float*)d_in[12];
    const float* en_b2 = (const float*)d_in[13];
    const float* ty_w1 = (const float*)d_in[14];
    const float* ty_b1 = (const float*)d_in[15];
    const float* ty_g  = (const float*)d_in[16];
    const float* ty_be = (const float*)d_in[17];
    const float* ty_w2 = (const float*)d_in[18];
    const float* ty_b2 = (const float*)d_in[19];

    float* out = (float*)d_out;
    float* wsf = (float*)d_ws;
    int* wsi = (int*)d_ws;
    _Float16* img = (_Float16*)(wsf + WS_IMG);

    k_prep<<<32, 256, 0, stream>>>(sc_w1, img);
    k_score3<<<(BATCH * S_LEN) / 64, 256, 0, stream>>>(
        X, img, sc_b1, sc_g, sc_be, sc_w2, sc_b2, MASK, wsf + WS_SCORES, out);
    k_spans<<<BATCH, 1024, 0, stream>>>(
        wsf + WS_SCORES, wsi + WS_SPSTART, wsi + WS_SPLEN, wsf + WS_SPAVG,
        wsi + WS_NSP, wsi + WS_SELSTART, wsi + WS_SELLEN, wsf + WS_SELAVG,
        wsf + WS_SELVALID, out);
    k_tail2<<<NSLOT, 1024, 0, stream>>>(
        X, wsi + WS_SELSTART, wsi + WS_SELLEN, wsf + WS_SELVALID,
        en_w1, en_b1, en_g, en_be, en_w2, en_b2,
        ty_w1, ty_b1, ty_g, ty_be, ty_w2, ty_b2, out);
}

// Round 7
// 154.644 us; speedup vs baseline: 1.6453x; 1.0067x over previous
//
#include <hip/hip_runtime.h>
#include <hip/hip_bf16.h>

#define S_LEN 4096
#define BATCH 8
#define DMODEL 1024
#define HDIM 256
#define NTYPES 8
#define KMAX 20
#define NSLOT (BATCH*KMAX)
#define THRESH 0.4f
#define LN_EPS 1e-5f
#define RSQRT2 0.70710678118654752f

// d_out offsets (f32 elements), reference return order
#define O_SCORES 0
#define O_ENH    32768
#define O_TLOG   196608
#define O_ESC    197888
#define O_TPROB  198048
#define O_TYPE   199328
#define O_VALIDK 199488

// ws layout (4-byte units)
#define WS_SCORES   0        // 32768 f32
#define WS_SPSTART  32768    // 16384 i32
#define WS_SPLEN    49152    // 16384 i32
#define WS_SPAVG    65536    // 16384 f32
#define WS_NSP      81920    // 8 i32
#define WS_SELSTART 81936    // 160 i32
#define WS_SELLEN   82096    // 160 i32
#define WS_SELAVG   82256    // 160 f32
#define WS_SELVALID 82416    // 160 f32
// W1 hi/lo f16 image: 32 chunks x 16384 f16 (Bh[8192] || Bl[8192] per chunk),
// exact LDS byte image (swizzle pre-baked) for global_load_lds.
#define WS_IMG      82576    // 262144 f32 units = 1 MB

typedef _Float16 f16x8 __attribute__((ext_vector_type(8)));
typedef float f32x16 __attribute__((ext_vector_type(16)));

__device__ __forceinline__ float gelu_exact(float v) {
    return 0.5f * v * (1.0f + erff(v * RSQRT2));
}
// swizzle key: spreads fixed-kg fragment reads across LDS 16B-slots
__device__ __forceinline__ int kkey(int r) { return (r ^ (r >> 2)) & 3; }

// async global->LDS, 16 B per lane (dest = wave-uniform base + lane*16)
#define GLL16(g, l) __builtin_amdgcn_global_load_lds( \
    (const __attribute__((address_space(1))) unsigned int*)(g), \
    (__attribute__((address_space(3))) unsigned int*)(l), 16, 0, 0)

// ---------------- K0: W1 -> linear LDS image (hi || lo per chunk) ----------------
__global__ __launch_bounds__(256) void k_prep(
    const float* __restrict__ W1, _Float16* __restrict__ IMG)
{
    const int c = blockIdx.x;     // k-chunk 0..31
    const int n = threadIdx.x;    // col 0..255
#pragma unroll
    for (int j = 0; j < 4; j++) {
        f16x8 hv, lv;
#pragma unroll
        for (int e = 0; e < 8; e++) {
            float w = W1[(size_t)(c * 32 + j * 8 + e) * HDIM + n];
            _Float16 h = (_Float16)w;
            hv[e] = h;
            lv[e] = (_Float16)(w - (float)h);
        }
        int off = c * 16384 + n * 32 + ((j ^ kkey(n)) * 8);
        *(f16x8*)&IMG[off] = hv;
        *(f16x8*)&IMG[off + 8192] = lv;
    }
}

// ---------------- K1: scorer MLP, 3-deep counted-vmcnt pipelined MFMA ----------
// 256 blocks x 512 thr (8 waves); tile 128 tok x 256 col; BK=32; wave 32x128
__global__ __launch_bounds__(512, 2) void k_score4(
    const float* __restrict__ X, const _Float16* __restrict__ IMG,
    const float* __restrict__ B1, const float* __restrict__ G,
    const float* __restrict__ BE, const float* __restrict__ W2,
    const float* __restrict__ B2, const int* __restrict__ MASK,
    float* __restrict__ scf, float* __restrict__ out)
{
    union SM {
        struct {
            _Float16 A[2][2][4096];   // [buf][hi/lo][row*32+xor*8]  32 KB
            _Float16 B[3][16384];     // [buf][Bh[8192] || Bl[8192]] 96 KB
        } s;
        struct { float part2[128 * 3]; float mul[128]; float rsl[128]; } e;
    };
    __shared__ SM sm;

    const int tid = threadIdx.x;
    const int lane = tid & 63, wid = tid >> 6;
    const int lr = lane & 31, lh = lane >> 5;
    const int wm = (wid & 3) * 32;       // wave token offset {0,32,64,96}
    const int wn = (wid >> 2) * 128;     // wave col offset {0,128}
    const int wg = wid >> 2;
    const int tok0 = blockIdx.x * 128;

    const int arow = tid >> 2, akg = tid & 3;
    const int aoff = arow * 32 + ((akg ^ kkey(arow)) * 8);
    const float* xptr = X + (size_t)(tok0 + arow) * DMODEL + akg * 8;
    const char* gB = (const char*)IMG + wid * 4096 + lane * 16;

    f32x16 acc[4];
#pragma unroll
    for (int ni = 0; ni < 4; ni++) acc[ni] = (f32x16)0.0f;

    // ---- prologue: X(0)->A0; stage B(0)->buf0, B(1)->buf1 ----
    {
        float4 xa = *(const float4*)xptr;              // X first (oldest vmcnt)
        float4 xb = *(const float4*)(xptr + 4);
        char* lB0 = (char*)sm.s.B[0] + wid * 4096;
        char* lB1 = (char*)sm.s.B[1] + wid * 4096;
#pragma unroll
        for (int r = 0; r < 4; r++) GLL16(gB + r * 1024, lB0 + r * 1024);
#pragma unroll
        for (int r = 0; r < 4; r++) GLL16(gB + 32768 + r * 1024, lB1 + r * 1024);
        float xv[8] = {xa.x, xa.y, xa.z, xa.w, xb.x, xb.y, xb.z, xb.w};
        f16x8 ah, al;
#pragma unroll
        for (int e = 0; e < 8; e++) {
            _Float16 h = (_Float16)xv[e];
            ah[e] = h;
            al[e] = (_Float16)(xv[e] - (float)h);
        }
        *(f16x8*)&sm.s.A[0][0][aoff] = ah;
        *(f16x8*)&sm.s.A[0][1][aoff] = al;
    }
    // drain B(0) (oldest 4) + A ds_writes; keep B(1)'s 4 in flight
    asm volatile("s_waitcnt vmcnt(4) lgkmcnt(0)" ::: "memory");
    __builtin_amdgcn_s_barrier();
    __builtin_amdgcn_sched_barrier(0);

    int bc = 0;   // buffer holding chunk c
    int ac = 0;   // A buffer holding chunk c
    for (int c = 0; c < 32; ++c) {
        const int cn = (c + 1) & 31;   // wrapped: keeps loop body branch-free
        const int c2 = (c + 2) & 31;
        int b2 = bc - 1; if (b2 < 0) b2 = 2;   // (bc+2)%3
        // issue X(c+1) (oldest), then B(c+2) GLLs (newest 4)
        float4 nxa = *(const float4*)(xptr + cn * 32);
        float4 nxb = *(const float4*)(xptr + cn * 32 + 4);
        {
            char* lB = (char*)sm.s.B[b2] + wid * 4096;
            const char* g = (const char*)IMG + (size_t)c2 * 32768 + wid * 4096 + lane * 16;
#pragma unroll
            for (int r = 0; r < 4; r++) GLL16(g + r * 1024, lB + r * 1024);
        }
        // compute chunk c (B(c) guaranteed complete by previous barrier discipline)
        {
            const _Float16* Ah = sm.s.A[ac][0];
            const _Float16* Al = sm.s.A[ac][1];
            const _Float16* Bc = sm.s.B[bc];
#pragma unroll
            for (int s = 0; s < 2; ++s) {
                const int kg = s * 2 + lh;
                const int row = wm + lr;
                const int oa = row * 32 + ((kg ^ kkey(row)) * 8);
                f16x8 fah = *(const f16x8*)&Ah[oa];
                f16x8 fal = *(const f16x8*)&Al[oa];
#pragma unroll
                for (int ni = 0; ni < 4; ni++) {
                    const int col = wn + ni * 32 + lr;
                    const int ob = col * 32 + ((kg ^ kkey(col)) * 8);
                    f16x8 fbh = *(const f16x8*)&Bc[ob];
                    f16x8 fbl = *(const f16x8*)&Bc[8192 + ob];
                    acc[ni] = __builtin_amdgcn_mfma_f32_32x32x16_f16(fah, fbh, acc[ni], 0, 0, 0);
                    acc[ni] = __builtin_amdgcn_mfma_f32_32x32x16_f16(fal, fbh, acc[ni], 0, 0, 0);
                    acc[ni] = __builtin_amdgcn_mfma_f32_32x32x16_f16(fah, fbl, acc[ni], 0, 0, 0);
                }
            }
        }
        // convert X(c+1) -> A[ac^1] (compiler waits X with counted vmcnt: 4 GLLs newer)
        {
            float xv[8] = {nxa.x, nxa.y, nxa.z, nxa.w, nxb.x, nxb.y, nxb.z, nxb.w};
            f16x8 ah, al;
#pragma unroll
            for (int e = 0; e < 8; e++) {
                _Float16 h = (_Float16)xv[e];
                ah[e] = h;
                al[e] = (_Float16)(xv[e] - (float)h);
            }
            *(f16x8*)&sm.s.A[ac ^ 1][0][aoff] = ah;
            *(f16x8*)&sm.s.A[ac ^ 1][1][aoff] = al;
        }
        // counted barrier: keep B(c+2)'s 4 loads in flight (never vmcnt(0))
        asm volatile("s_waitcnt vmcnt(4) lgkmcnt(0)" ::: "memory");
        __builtin_amdgcn_s_barrier();
        __builtin_amdgcn_sched_barrier(0);
        bc = bc == 2 ? 0 : bc + 1;
        ac ^= 1;
    }

    __syncthreads();   // full drain; union becomes epilogue arrays

    // ---- epilogue: bias, LN over 256 cols, GELU, dot w2, sigmoid, mask ----
    // C/D: col = wn+ni*32+lr, row = wm+(r&3)+8*(r>>2)+4*lh
    float bcol[4], gcol[4], becol[4], wcol[4];
#pragma unroll
    for (int ni = 0; ni < 4; ni++) {
        int colg = wn + ni * 32 + lr;
        bcol[ni] = B1[colg];
        gcol[ni] = G[colg];
        becol[ni] = BE[colg];
        wcol[ni] = W2[colg];
    }
#pragma unroll
    for (int ni = 0; ni < 4; ni++)
#pragma unroll
        for (int r = 0; r < 16; r++) acc[ni][r] += bcol[ni];

    // pass 1: mean
#pragma unroll
    for (int r = 0; r < 16; r++) {
        float p = acc[0][r] + acc[1][r] + acc[2][r] + acc[3][r];
        p += __shfl_xor(p, 1);  p += __shfl_xor(p, 2);
        p += __shfl_xor(p, 4);  p += __shfl_xor(p, 8);
        p += __shfl_xor(p, 16);
        int row = wm + (r & 3) + 8 * (r >> 2) + 4 * lh;
        if (lr == 0) sm.e.part2[row * 3 + wg] = p;
    }
    __syncthreads();
    if (tid < 128)
        sm.e.mul[tid] = (sm.e.part2[tid * 3] + sm.e.part2[tid * 3 + 1]) * (1.0f / 256.0f);
    __syncthreads();
    // pass 2: variance
#pragma unroll
    for (int r = 0; r < 16; r++) {
        int row = wm + (r & 3) + 8 * (r >> 2) + 4 * lh;
        float m = sm.e.mul[row];
        float p = 0.0f;
#pragma unroll
        for (int ni = 0; ni < 4; ni++) {
            float d = acc[ni][r] - m;
            p += d * d;
        }
        p += __shfl_xor(p, 1);  p += __shfl_xor(p, 2);
        p += __shfl_xor(p, 4);  p += __shfl_xor(p, 8);
        p += __shfl_xor(p, 16);
        if (lr == 0) sm.e.part2[row * 3 + wg] = p;
    }
    __syncthreads();
    if (tid < 128)
        sm.e.rsl[tid] = rsqrtf((sm.e.part2[tid * 3] + sm.e.part2[tid * 3 + 1]) * (1.0f / 256.0f) + LN_EPS);
    __syncthreads();
    // pass 3: LN affine + GELU + dot w2
#pragma unroll
    for (int r = 0; r < 16; r++) {
        int row = wm + (r & 3) + 8 * (r >> 2) + 4 * lh;
        float m = sm.e.mul[row];
        float rv = sm.e.rsl[row];
        float p = 0.0f;
#pragma unroll
        for (int ni = 0; ni < 4; ni++) {
            float v = (acc[ni][r] - m) * rv * gcol[ni] + becol[ni];
            p += gelu_exact(v) * wcol[ni];
        }
        p += __shfl_xor(p, 1);  p += __shfl_xor(p, 2);
        p += __shfl_xor(p, 4);  p += __shfl_xor(p, 8);
        p += __shfl_xor(p, 16);
        if (lr == 0) sm.e.part2[row * 3 + wg] = p;
    }
    __syncthreads();
    if (tid < 128) {
        float s = sm.e.part2[tid * 3] + sm.e.part2[tid * 3 + 1];
        float logit = s + B2[0];
        float sc = 1.0f / (1.0f + expf(-logit));
        int t = tok0 + tid;
        sc *= (float)MASK[t];
        scf[t] = sc;
        out[O_SCORES + t] = sc;
    }
}

// ---------------- K2: span RLE + top-20 per row ----------------
__global__ __launch_bounds__(1024) void k_spans(
    const float* __restrict__ scf, int* __restrict__ spstart,
    int* __restrict__ splen, float* __restrict__ spavg, int* __restrict__ nsp,
    int* __restrict__ selstart, int* __restrict__ sellen,
    float* __restrict__ selavg, float* __restrict__ selvalid,
    float* __restrict__ out)
{
    const int r = blockIdx.x, tid = threadIdx.x;
    __shared__ float sc[S_LEN];
    __shared__ unsigned char ab[S_LEN];
    __shared__ int scn[1024];
    __shared__ float avgl[2048];
    __shared__ float rv[16];
    __shared__ int ri[16];

    float4 v = ((const float4*)(scf + (size_t)r * S_LEN))[tid];
    const int s0 = tid * 4;
    sc[s0 + 0] = v.x; sc[s0 + 1] = v.y; sc[s0 + 2] = v.z; sc[s0 + 3] = v.w;
    ab[s0 + 0] = (v.x >= THRESH);
    ab[s0 + 1] = (v.y >= THRESH);
    ab[s0 + 2] = (v.z >= THRESH);
    ab[s0 + 3] = (v.w >= THRESH);
    __syncthreads();

    bool st[4];
    int cnt = 0;
#pragma unroll
    for (int i = 0; i < 4; i++) {
        bool a = ab[s0 + i] != 0;
        bool p = (s0 + i == 0) ? false : (ab[s0 + i - 1] != 0);
        st[i] = a && !p;
        cnt += st[i] ? 1 : 0;
    }
    scn[tid] = cnt;
    __syncthreads();
    for (int off = 1; off < 1024; off <<= 1) {
        int mine = scn[tid];
        int add = (tid >= off) ? scn[tid - off] : 0;
        __syncthreads();
        scn[tid] = mine + add;
        __syncthreads();
    }
    const int total = scn[1023];
    int j = scn[tid] - cnt;
    for (int i = 0; i < 4; i++) {
        if (st[i]) {
            int s = s0 + i;
            float sum = 0.0f;
            int len = 0;
            int e = s;
            while (e < S_LEN && ab[e]) { sum += sc[e]; len++; e++; }
            float avg = sum / (float)len;
            spstart[r * 2048 + j] = s;
            splen[r * 2048 + j] = len;
            spavg[r * 2048 + j] = avg;
            avgl[j] = avg;
            j++;
        }
    }
    if (tid == 0) nsp[r] = total;
    __syncthreads();

    for (int k = 0; k < KMAX; k++) {
        float bv = -3.0e38f;
        int bi = 0x7FFFFFFF;
        for (int q = tid; q < total; q += 1024) {
            float a = avgl[q];
            if (a > bv) { bv = a; bi = q; }
        }
#pragma unroll
        for (int m = 1; m < 64; m <<= 1) {
            float ov = __shfl_xor(bv, m);
            int oi = __shfl_xor(bi, m);
            if (ov > bv || (ov == bv && oi < bi)) { bv = ov; bi = oi; }
        }
        if ((tid & 63) == 0) { rv[tid >> 6] = bv; ri[tid >> 6] = bi; }
        __syncthreads();
        if (tid < 64) {
            float v2 = (tid < 16) ? rv[tid] : -3.0e38f;
            int i2 = (tid < 16) ? ri[tid] : 0x7FFFFFFF;
#pragma unroll
            for (int m = 1; m < 16; m <<= 1) {
                float ov = __shfl_xor(v2, m);
                int oi = __shfl_xor(i2, m);
                if (ov > v2 || (ov == v2 && oi < i2)) { v2 = ov; i2 = oi; }
            }
            if (tid == 0) {
                int slot = r * KMAX + k;
                if (k < total) {
                    avgl[i2] = -3.0e38f;
                    int ln = splen[r * 2048 + i2];
                    float vd = (v2 >= THRESH && ln > 0) ? 1.0f : 0.0f;
                    selstart[slot] = spstart[r * 2048 + i2];
                    sellen[slot] = ln;
                    selavg[slot] = v2;
                    selvalid[slot] = vd;
                    out[O_ESC + slot] = v2 * vd;
                    out[O_VALIDK + slot] = vd;
                } else {
                    selstart[slot] = -1;
                    sellen[slot] = 0;
                    selavg[slot] = -1.0f;
                    selvalid[slot] = 0.0f;
                    out[O_ESC + slot] = 0.0f;
                    out[O_VALIDK + slot] = 0.0f;
                }
            }
        }
        __syncthreads();
    }
}

// ---------------- K3: fused tail, 1024 threads (16 waves, 4/SIMD) ----------------
__global__ __launch_bounds__(1024) void k_tail2(
    const float* __restrict__ X, const int* __restrict__ selstart,
    const int* __restrict__ sellen, const float* __restrict__ selvalid,
    const float* __restrict__ en_w1, const float* __restrict__ en_b1,
    const float* __restrict__ en_g, const float* __restrict__ en_be,
    const float* __restrict__ en_w2, const float* __restrict__ en_b2,
    const float* __restrict__ ty_w1, const float* __restrict__ ty_b1,
    const float* __restrict__ ty_g, const float* __restrict__ ty_be,
    const float* __restrict__ ty_w2, const float* __restrict__ ty_b2,
    float* __restrict__ out)
{
    const int slot = blockIdx.x, tid = threadIdx.x;
    __shared__ float xr[DMODEL];
    __shared__ float ps[DMODEL];
    __shared__ float g1[HDIM];
    __shared__ float red[8];
    __shared__ float lgp[4 * NTYPES];
    __shared__ float lg[NTYPES];

    const int r = slot / KMAX;
    const int s0 = selstart[slot], ln = sellen[slot];
    const float vd = selvalid[slot];
    const int j = tid & 255, p = tid >> 8;

    {
        float a = 0.0f;
        if (s0 >= 0) {
            const float* base = X + ((size_t)r * S_LEN + s0) * DMODEL + tid;
#pragma unroll 4
            for (int t = 0; t < ln; t++) a += base[(size_t)t * DMODEL];
        }
        const float dn = (ln > 0) ? (float)ln : 1.0f;
        xr[tid] = a / dn * vd;
    }
    __syncthreads();

    {
        float acc = 0.0f;
        const float* wp = en_w1 + (size_t)(p * 256) * HDIM + j;
        const float* xp = xr + p * 256;
#pragma unroll 16
        for (int k = 0; k < 256; k++) acc += xp[k] * wp[(size_t)k * HDIM];
        ps[tid] = acc;
    }
    __syncthreads();
    float h = 0.0f, mu = 0.0f;
    if (tid < 256) {
        h = ps[tid] + ps[256 + tid] + ps[512 + tid] + ps[768 + tid] + en_b1[tid];
        float s = h;
#pragma unroll
        for (int m = 1; m < 64; m <<= 1) s += __shfl_xor(s, m);
        if ((tid & 63) == 0) red[tid >> 6] = s;
    }
    __syncthreads();
    if (tid < 256) {
        mu = (red[0] + red[1] + red[2] + red[3]) * (1.0f / 256.0f);
        float d = h - mu;
        float s = d * d;
#pragma unroll
        for (int m = 1; m < 64; m <<= 1) s += __shfl_xor(s, m);
        if ((tid & 63) == 0) red[4 + (tid >> 6)] = s;
    }
    __syncthreads();
    if (tid < 256) {
        float var = (red[4] + red[5] + red[6] + red[7]) * (1.0f / 256.0f);
        float v = (h - mu) * rsqrtf(var + LN_EPS) * en_g[tid] + en_be[tid];
        g1[tid] = gelu_exact(v);
    }
    __syncthreads();

    {
        float acc = en_b2[tid];
        const float* wp = en_w2 + tid;
#pragma unroll 16
        for (int k = 0; k < 256; k++) acc += g1[k] * wp[(size_t)k * DMODEL];
        acc *= vd;
        out[O_ENH + (size_t)slot * DMODEL + tid] = acc;
        xr[tid] = acc;
    }
    __syncthreads();

    {
        float acc = 0.0f;
        const float* wp = ty_w1 + (size_t)(p * 256) * HDIM + j;
        const float* xp = xr + p * 256;
#pragma unroll 16
        for (int k = 0; k < 256; k++) acc += xp[k] * wp[(size_t)k * HDIM];
        ps[tid] = acc;
    }
    __syncthreads();
    h = 0.0f; mu = 0.0f;
    if (tid < 256) {
        h = ps[tid] + ps[256 + tid] + ps[512 + tid] + ps[768 + tid] + ty_b1[tid];
        float s = h;
#pragma unroll
        for (int m = 1; m < 64; m <<= 1) s += __shfl_xor(s, m);
        if ((tid & 63) == 0) red[tid >> 6] = s;
    }
    __syncthreads();
    if (tid < 256) {
        mu = (red[0] + red[1] + red[2] + red[3]) * (1.0f / 256.0f);
        float d = h - mu;
        float s = d * d;
#pragma unroll
        for (int m = 1; m < 64; m <<= 1) s += __shfl_xor(s, m);
        if ((tid & 63) == 0) red[4 + (tid >> 6)] = s;
    }
    __syncthreads();
    if (tid < 256) {
        float var = (red[4] + red[5] + red[6] + red[7]) * (1.0f / 256.0f);
        float v = (h - mu) * rsqrtf(var + LN_EPS) * ty_g[tid] + ty_be[tid];
        g1[tid] = gelu_exact(v);
    }
    __syncthreads();

    if (tid < 256) {
        float gv = g1[tid];
        float4 w0 = *(const float4*)&ty_w2[tid * NTYPES];
        float4 w1v = *(const float4*)&ty_w2[tid * NTYPES + 4];
        float pj[8] = {gv * w0.x, gv * w0.y, gv * w0.z, gv * w0.w,
                       gv * w1v.x, gv * w1v.y, gv * w1v.z, gv * w1v.w};
#pragma unroll
        for (int q = 0; q < 8; q++) {
            float s = pj[q];
#pragma unroll
            for (int m = 1; m < 64; m <<= 1) s += __shfl_xor(s, m);
            pj[q] = s;
        }
        if ((tid & 63) == 0) {
#pragma unroll
            for (int q = 0; q < 8; q++) lgp[(tid >> 6) * NTYPES + q] = pj[q];
        }
    }
    __syncthreads();
    if (tid < NTYPES) {
        float la = ty_b2[tid] + lgp[tid] + lgp[NTYPES + tid] +
                   lgp[2 * NTYPES + tid] + lgp[3 * NTYPES + tid];
        lg[tid] = la;
        out[O_TLOG + slot * NTYPES + tid] = la;
    }
    __syncthreads();
    if (tid == 0) {
        float mx = lg[0];
        int am = 0;
        for (int t = 1; t < NTYPES; t++)
            if (lg[t] > mx) { mx = lg[t]; am = t; }
        float ex[NTYPES], ssum = 0.0f;
        for (int t = 0; t < NTYPES; t++) { ex[t] = expf(lg[t] - mx); ssum += ex[t]; }
        for (int t = 0; t < NTYPES; t++)
            out[O_TPROB + slot * NTYPES + t] = ex[t] / ssum;
        out[O_TYPE + slot] = (float)am;
    }
}

extern "C" void kernel_launch(void* const* d_in, const int* in_sizes, int n_in,
                              void* d_out, int out_size, void* d_ws, size_t ws_size,
                              hipStream_t stream) {
    const float* X = (const float*)d_in[0];
    const int* MASK = (const int*)d_in[1];
    const float* sc_w1 = (const float*)d_in[2];
    const float* sc_b1 = (const float*)d_in[3];
    const float* sc_g  = (const float*)d_in[4];
    const float* sc_be = (const float*)d_in[5];
    const float* sc_w2 = (const float*)d_in[6];
    const float* sc_b2 = (const float*)d_in[7];
    const float* en_w1 = (const float*)d_in[8];
    const float* en_b1 = (const float*)d_in[9];
    const float* en_g  = (const float*)d_in[10];
    const float* en_be = (const float*)d_in[11];
    const float* en_w2 = (const float*)d_in[12];
    const float* en_b2 = (const float*)d_in[13];
    const float* ty_w1 = (const float*)d_in[14];
    const float* ty_b1 = (const float*)d_in[15];
    const float* ty_g  = (const float*)d_in[16];
    const float* ty_be = (const float*)d_in[17];
    const float* ty_w2 = (const float*)d_in[18];
    const float* ty_b2 = (const float*)d_in[19];

    float* out = (float*)d_out;
    float* wsf = (float*)d_ws;
    int* wsi = (int*)d_ws;
    _Float16* img = (_Float16*)(wsf + WS_IMG);

    k_prep<<<32, 256, 0, stream>>>(sc_w1, img);
    k_score4<<<(BATCH * S_LEN) / 128, 512, 0, stream>>>(
        X, img, sc_b1, sc_g, sc_be, sc_w2, sc_b2, MASK, wsf + WS_SCORES, out);
    k_spans<<<BATCH, 1024, 0, stream>>>(
        wsf + WS_SCORES, wsi + WS_SPSTART, wsi + WS_SPLEN, wsf + WS_SPAVG,
        wsi + WS_NSP, wsi + WS_SELSTART, wsi + WS_SELLEN, wsf + WS_SELAVG,
        wsf + WS_SELVALID, out);
    k_tail2<<<NSLOT, 1024, 0, stream>>>(
        X, wsi + WS_SELSTART, wsi + WS_SELLEN, wsf + WS_SELVALID,
        en_w1, en_b1, en_g, en_be, en_w2, en_b2,
        ty_w1, ty_b1, ty_g, ty_be, ty_w2, ty_b2, out);
}